// Round 4
// baseline (473.963 us; speedup 1.0000x reference)
//
#include <hip/hip_runtime.h>

// DualMemoryBlock: rmsnorm -> {windowed attn, oscillator TRN} -> gated mix -> SwiGLU FFN
// bf16 MFMA 16x16x32, 128x128 tile, global_load_lds(16B) staging.
// R4: BK=64 K-loop (paired 128x32 LDS buffers, half the barriers); qkv+trn-drive
// merged GEMM (N=3200); down-GEMM atomics straight into out (no reduce pass);
// attention V^T staging across all 256 threads.

typedef unsigned short u16;
typedef unsigned short u16x8 __attribute__((ext_vector_type(8)));
typedef __bf16 bf16x8 __attribute__((ext_vector_type(8)));
typedef float f32x4 __attribute__((ext_vector_type(4)));

#define DI static __device__ __forceinline__

DI u16 f2b(float f){
  union { float f; unsigned u; } v; v.f = f;
  unsigned r = v.u + 0x7FFFu + ((v.u >> 16) & 1u);
  return (u16)(r >> 16);
}
DI float b2f(u16 b){
  union { unsigned u; float f; } v; v.u = ((unsigned)b) << 16; return v.f;
}
DI u16x8 ld8(const u16* p){ return *(const u16x8*)p; }

DI f32x4 MFMA16(u16x8 a, u16x8 b, f32x4 c){
  return __builtin_amdgcn_mfma_f32_16x16x32_bf16(
      __builtin_bit_cast(bf16x8, a), __builtin_bit_cast(bf16x8, b), c, 0, 0, 0);
}

DI void async16(const void* g, void* l){
  void* gg = const_cast<void*>(g);
  __builtin_amdgcn_global_load_lds(
      (__attribute__((address_space(1))) void*)gg,
      (__attribute__((address_space(3))) void*)l, 16, 0, 0);
}

// ---------------------------------------------------------------------------
// Weight conversion fp32 -> bf16, packed. Element offsets:
//  qkv [3072x1024]                     0 .. 3145728
//  wct [128x1024] win|gate|zeros       3145728 .. 3276800   (adjacent to qkv!)
//  proj [1024x1024]                    3276800 .. 4325376
//  gate+up group-interleaved [8192x1024] 4325376 .. 12713984
//  down [1024x4096]                    12713984 .. 16908288
//  wout [1024x32]                      16908288 .. 16941056
// ---------------------------------------------------------------------------
__global__ __launch_bounds__(256) void convert_w(
    const float* __restrict__ qkvw, const float* __restrict__ projw,
    const float* __restrict__ fgw, const float* __restrict__ fuw,
    const float* __restrict__ fdw, const float* __restrict__ twin,
    const float* __restrict__ tgw, const float* __restrict__ twout,
    u16* __restrict__ dst)
{
  size_t i = (size_t)blockIdx.x * 256 + threadIdx.x;
  if (i >= 4235264u) return;
  size_t e = i * 4;
  float4 v;
  if (e < 3145728u)        v = *(const float4*)(qkvw + e);
  else if (e < 3276800u){
    size_t i2 = e - 3145728u;
    int row = (int)(i2 >> 10), c = (int)(i2 & 1023);
    if (row < 32)      v = *(const float4*)(twin + row * 1024 + c);
    else if (row < 64) v = *(const float4*)(tgw + (row - 32) * 1024 + c);
    else               v = make_float4(0.f, 0.f, 0.f, 0.f);
  }
  else if (e < 4325376u)   v = *(const float4*)(projw + (e - 3276800u));
  else if (e < 12713984u){
    size_t i2 = e - 4325376u;
    int row = (int)(i2 >> 10), c = (int)(i2 & 1023);
    int G = row >> 5, j = row & 31;
    const float* src = (j < 16) ? fgw : fuw;
    v = *(const float4*)(src + (size_t)(G * 16 + (j & 15)) * 1024 + c);
  }
  else if (e < 16908288u)  v = *(const float4*)(fdw + (e - 12713984u));
  else                     v = *(const float4*)(twout + (e - 16908288u));
  uint2 p;
  p.x = (unsigned)f2b(v.x) | ((unsigned)f2b(v.y) << 16);
  p.y = (unsigned)f2b(v.z) | ((unsigned)f2b(v.w) << 16);
  *(uint2*)(dst + e) = p;
}

// ---------------------------------------------------------------------------
// RMSNorm (+ fused scalar gate logit for norm1)
// ---------------------------------------------------------------------------
__global__ __launch_bounds__(256) void rmsnorm_gate(
    const float* __restrict__ x, const float* __restrict__ w,
    const float* __restrict__ gw, const float* __restrict__ gb,
    u16* __restrict__ h, float* __restrict__ g)
{
  const int row = blockIdx.x, tid = threadIdx.x;
  const int wave = tid >> 6, lane = tid & 63;
  __shared__ float sb[8];
  float4 xv = ((const float4*)(x + (size_t)row * 1024))[tid];
  float ss = xv.x*xv.x + xv.y*xv.y + xv.z*xv.z + xv.w*xv.w;
#pragma unroll
  for (int m = 32; m; m >>= 1) ss += __shfl_xor(ss, m);
  if (lane == 0) sb[wave] = ss;
  __syncthreads();
  float rstd = rsqrtf((sb[0]+sb[1]+sb[2]+sb[3]) * (1.f/1024.f) + 1e-6f);
  float4 wv = ((const float4*)w)[tid];
  float h0 = xv.x*rstd*wv.x, h1 = xv.y*rstd*wv.y;
  float h2v = xv.z*rstd*wv.z, h3 = xv.w*rstd*wv.w;
  uint2 pk;
  pk.x = (unsigned)f2b(h0) | ((unsigned)f2b(h1) << 16);
  pk.y = (unsigned)f2b(h2v) | ((unsigned)f2b(h3) << 16);
  ((uint2*)(h + (size_t)row * 1024))[tid] = pk;
  float4 gv = ((const float4*)gw)[tid];
  float gd = h0*gv.x + h1*gv.y + h2v*gv.z + h3*gv.w;
#pragma unroll
  for (int m = 32; m; m >>= 1) gd += __shfl_xor(gd, m);
  if (lane == 0) sb[4 + wave] = gd;
  __syncthreads();
  if (tid == 0) g[row] = 1.f / (1.f + __expf(-(sb[4]+sb[5]+sb[6]+sb[7] + gb[0])));
}

// ---------------------------------------------------------------------------
// Fused: proj split-K reduce + bias + gated mix + rmsnorm2.
// out = x + g*(p0+p1+projb) + (1-g)*trn ; h2 = bf16(rms(out)*n2w)
// (down-GEMM later atomically adds the FFN result into out)
// ---------------------------------------------------------------------------
__global__ __launch_bounds__(256) void reduce_mix_norm(
    const float* __restrict__ part, const float* __restrict__ x,
    const u16* __restrict__ trn, const float* __restrict__ g,
    const float* __restrict__ pb, const float* __restrict__ n2w,
    float* __restrict__ out, u16* __restrict__ h2)
{
  const int row = blockIdx.x, tid = threadIdx.x;
  const int wave = tid >> 6, lane = tid & 63;
  __shared__ float sb[4];
  const size_t ro = (size_t)row * 1024;
  float4 p0 = ((const float4*)(part + ro))[tid];
  float4 p1 = ((const float4*)(part + 4194304 + ro))[tid];
  float4 bb = ((const float4*)pb)[tid];
  float4 xv = ((const float4*)(x + ro))[tid];
  uint2 tz = ((const uint2*)(trn + ro))[tid];
  float gg = g[row];
  float t0 = b2f((u16)tz.x), t1 = b2f((u16)(tz.x >> 16));
  float t2 = b2f((u16)tz.y), t3 = b2f((u16)(tz.y >> 16));
  float m0 = xv.x + gg*(p0.x+p1.x+bb.x) + (1.f-gg)*t0;
  float m1 = xv.y + gg*(p0.y+p1.y+bb.y) + (1.f-gg)*t1;
  float m2 = xv.z + gg*(p0.z+p1.z+bb.z) + (1.f-gg)*t2;
  float m3 = xv.w + gg*(p0.w+p1.w+bb.w) + (1.f-gg)*t3;
  float4 mo; mo.x = m0; mo.y = m1; mo.z = m2; mo.w = m3;
  ((float4*)(out + ro))[tid] = mo;
  float ss = m0*m0 + m1*m1 + m2*m2 + m3*m3;
#pragma unroll
  for (int m = 32; m; m >>= 1) ss += __shfl_xor(ss, m);
  if (lane == 0) sb[wave] = ss;
  __syncthreads();
  float rstd = rsqrtf((sb[0]+sb[1]+sb[2]+sb[3]) * (1.f/1024.f) + 1e-6f);
  float4 wv = ((const float4*)n2w)[tid];
  uint2 pk;
  pk.x = (unsigned)f2b(m0*rstd*wv.x) | ((unsigned)f2b(m1*rstd*wv.y) << 16);
  pk.y = (unsigned)f2b(m2*rstd*wv.z) | ((unsigned)f2b(m3*rstd*wv.w) << 16);
  ((uint2*)(h2 + ro))[tid] = pk;
}

// ---------------------------------------------------------------------------
// GEMM: out[m,n] = sum_k A[m,k]*B[n,k]  (row-major bf16, fp32 accum)
// 128x128 tile, 256 thr = 2x2 waves; split-K via blockIdx.z.
// WIDE: BK=64 via two 128x32 LDS buffer pairs (one barrier pair per 64-K).
// MODE epilogues:
//  0: n0<3072 -> qkv bf16 + bias (stride 3072);
//     n0==3072 -> TRN drive: c2<32 u[b,k,t]=v; c2<64 tg=sigmoid(v+tgb)
//  3: atomicAdd(outF[rr*N+col], v)                        (ffn down into out)
//  6: outB = bf16(v * auxF[0])                            (trn_out, res_scale)
//  7: grouped gate/up: silu(acc[.][2p])*acc[.][2p+1]
//  8: partial fp32 store at z*M + rr*N + col              (proj split-K)
// ---------------------------------------------------------------------------
template<int MODE, bool WIDE>
__global__ __launch_bounds__(256) void gemm_bt(
    const u16* __restrict__ A, const u16* __restrict__ B,
    float* __restrict__ outF, float* __restrict__ outF2, u16* __restrict__ outB,
    const float* __restrict__ bias, const float* __restrict__ auxF,
    int M, int N, int K)
{
  __shared__ __align__(16) u16 sA[2][128 * 32];
  __shared__ __align__(16) u16 sB[2][128 * 32];
  const int tid = threadIdx.x;
  const int wave = tid >> 6, lane = tid & 63;
  const int lr = lane & 15, lq = lane >> 4;
  const int m0 = blockIdx.x * 128, n0 = blockIdx.y * 128;
  const int wm = (wave & 1) * 64, wn = (wave >> 1) * 64;
  const int ks = K / (int)gridDim.z;
  const int kbeg = (int)blockIdx.z * ks, kend = kbeg + ks;
  f32x4 acc[4][4] = {};
  const int srow = wave * 16 + (lane >> 2);
  const int scol = (lane & 3) * 8;
  const u16* gA = A + (size_t)(m0 + srow) * K + scol;
  const u16* gB = B + (size_t)(n0 + srow) * K + scol;
  u16* lA0 = &sA[0][(wave * 16) * 32];
  u16* lA1 = &sA[0][(64 + wave * 16) * 32];
  u16* lB0 = &sB[0][(wave * 16) * 32];
  u16* lB1 = &sB[0][(64 + wave * 16) * 32];
  const size_t K64 = (size_t)64 * K;
  const int BUF = 128 * 32;

  if (WIDE){
    for (int k0 = kbeg; k0 < kend; k0 += 64){
      async16(gA + k0,            lA0);
      async16(gA + K64 + k0,      lA1);
      async16(gB + k0,            lB0);
      async16(gB + K64 + k0,      lB1);
      async16(gA + k0 + 32,       lA0 + BUF);
      async16(gA + K64 + k0 + 32, lA1 + BUF);
      async16(gB + k0 + 32,       lB0 + BUF);
      async16(gB + K64 + k0 + 32, lB1 + BUF);
      __syncthreads();
      u16x8 af[4], bf[4];
#pragma unroll
      for (int i = 0; i < 4; i++) af[i] = ld8(&sA[0][(wm + i*16 + lr)*32 + lq*8]);
#pragma unroll
      for (int i = 0; i < 4; i++) bf[i] = ld8(&sB[0][(wn + i*16 + lr)*32 + lq*8]);
#pragma unroll
      for (int mi = 0; mi < 4; mi++)
#pragma unroll
        for (int ni = 0; ni < 4; ni++)
          acc[mi][ni] = MFMA16(af[mi], bf[ni], acc[mi][ni]);
#pragma unroll
      for (int i = 0; i < 4; i++) af[i] = ld8(&sA[1][(wm + i*16 + lr)*32 + lq*8]);
#pragma unroll
      for (int i = 0; i < 4; i++) bf[i] = ld8(&sB[1][(wn + i*16 + lr)*32 + lq*8]);
#pragma unroll
      for (int mi = 0; mi < 4; mi++)
#pragma unroll
        for (int ni = 0; ni < 4; ni++)
          acc[mi][ni] = MFMA16(af[mi], bf[ni], acc[mi][ni]);
      __syncthreads();
    }
  } else {
    for (int k0 = kbeg; k0 < kend; k0 += 32){
      async16(gA + k0,       lA0);
      async16(gA + K64 + k0, lA1);
      async16(gB + k0,       lB0);
      async16(gB + K64 + k0, lB1);
      __syncthreads();
      u16x8 af[4], bf[4];
#pragma unroll
      for (int i = 0; i < 4; i++) af[i] = ld8(&sA[0][(wm + i*16 + lr)*32 + lq*8]);
#pragma unroll
      for (int i = 0; i < 4; i++) bf[i] = ld8(&sB[0][(wn + i*16 + lr)*32 + lq*8]);
#pragma unroll
      for (int mi = 0; mi < 4; mi++)
#pragma unroll
        for (int ni = 0; ni < 4; ni++)
          acc[mi][ni] = MFMA16(af[mi], bf[ni], acc[mi][ni]);
      __syncthreads();
    }
  }

  if (MODE == 7){
    const int cb = ((n0 + wn) >> 1) + lr;   // packed col base
#pragma unroll
    for (int mi = 0; mi < 4; mi++){
      const int row = m0 + wm + mi*16 + lq*4;
#pragma unroll
      for (int p = 0; p < 2; p++){
        const int col = cb + p*16;
#pragma unroll
        for (int r = 0; r < 4; r++){
          float gv = acc[mi][2*p][r], uv = acc[mi][2*p+1][r];
          float rv = gv / (1.f + __expf(-gv)) * uv;
          outB[(size_t)(row + r) * (N >> 1) + col] = f2b(rv);
        }
      }
    }
    return;
  }

  float scale6 = 0.f;
  if (MODE == 6) scale6 = auxF[0];

#pragma unroll
  for (int mi = 0; mi < 4; mi++){
    const int row = m0 + wm + mi*16 + lq*4;
#pragma unroll
    for (int ni = 0; ni < 4; ni++){
      const int col = n0 + wn + ni*16 + lr;
#pragma unroll
      for (int r = 0; r < 4; r++){
        const int rr = row + r;
        float v = acc[mi][ni][r];
        if (MODE == 0){
          if (n0 < 3072){
            outB[(size_t)rr * 3072 + col] = f2b(v + bias[col]);
          } else {
            int c2 = col - 3072;
            int bb = rr >> 11, tt = rr & 2047;
            if (c2 < 32) outF[((size_t)bb * 32 + c2) * 2048 + tt] = v;
            else if (c2 < 64)
              outF2[(size_t)rr * 32 + (c2 - 32)] =
                  1.f / (1.f + __expf(-(v + auxF[c2 - 32])));
          }
        } else if (MODE == 3){
          atomicAdd(&outF[(size_t)rr * N + col], v);
        } else if (MODE == 6){
          outB[(size_t)rr * N + col] = f2b(v * scale6);
        } else if (MODE == 8){
          outF[(size_t)blockIdx.z * (size_t)M + (size_t)rr * N + col] = v;
        }
      }
    }
  }
}

// ---------------------------------------------------------------------------
// Windowed causal flash attention. qkv: [B*T, 3072] bf16 (q|k|v, 16 heads x 64).
// ---------------------------------------------------------------------------
__global__ __launch_bounds__(256) void attn_win(
    const u16* __restrict__ qkv, u16* __restrict__ ao)
{
  const int blk = blockIdx.x;
  const int tile = blk & 31, hh = (blk >> 5) & 15, b = blk >> 9;
  const int t0 = tile * 64;
  const int tid = threadIdx.x, wave = tid >> 6, lane = tid & 63;
  const int lr = lane & 15, lq = lane >> 4;
  const int qt = t0 + wave * 16;
  __shared__ __align__(16) u16 sVt[64 * 40];      // V^T, padded stride 40
  __shared__ __align__(16) u16 sP[4][16 * 32];    // per-wave P buffer

  const u16* base = qkv + (size_t)b * 2048 * 3072 + hh * 64;
  const u16* qrow = base + (size_t)(qt + lr) * 3072 + lq * 8;
  u16x8 qf0 = ld8(qrow), qf1 = ld8(qrow + 32);
  const u16* kbase = base + 1024;
  const u16* vbase = base + 2048;

  f32x4 o0 = {0,0,0,0}, o1 = {0,0,0,0}, o2 = {0,0,0,0}, o3 = {0,0,0,0};
  float mrun[4] = {-1e30f, -1e30f, -1e30f, -1e30f};
  float lrun[4] = {0.f, 0.f, 0.f, 0.f};
  const float c1 = 0.125f * 1.44269504088896f;  // scale * log2(e)

  const int kb = (t0 >= 256) ? (t0 - 256) : 0;
  const int ntl = (t0 + 64 - kb) >> 5;
  for (int it = 0; it < ntl; ++it){
    const int kt = kb + it * 32;
    __syncthreads();                 // prev-iter LDS reads done
    {                                // stage V^T (32 keys x 64 dims), all 256 thr
      const int key = tid & 31, dseg = tid >> 5;
      const u16* gv = vbase + (size_t)(kt + key) * 3072 + dseg * 8;
      u16x8 v0 = ld8(gv);
#pragma unroll
      for (int j = 0; j < 8; j++)
        sVt[(dseg*8 + j) * 40 + key] = v0[j];
    }
    __syncthreads();
    const bool active = (kt < qt + 16) && (kt + 286 >= qt);
    if (!active) continue;           // both barriers are above: counts stay equal

    f32x4 s0 = {0,0,0,0}, s1 = {0,0,0,0};
    {
      const u16* kr = kbase + (size_t)(kt + lr) * 3072 + lq * 8;
      u16x8 k00 = ld8(kr), k01 = ld8(kr + 32);
      const u16* kr1 = kr + (size_t)16 * 3072;
      u16x8 k10 = ld8(kr1), k11 = ld8(kr1 + 32);
      s0 = MFMA16(qf0, k00, s0); s0 = MFMA16(qf1, k01, s0);
      s1 = MFMA16(qf0, k10, s1); s1 = MFMA16(qf1, k11, s1);
    }
    float al[4];
#pragma unroll
    for (int r = 0; r < 4; r++){
      const int q = qt + lq * 4 + r;
      const int ca = kt + lr, cb = kt + 16 + lr;
      float a0 = (ca <= q && ca + 255 >= q) ? s0[r] : -1e30f;
      float a1 = (cb <= q && cb + 255 >= q) ? s1[r] : -1e30f;
      float mx = fmaxf(a0, a1);
      mx = fmaxf(mx, __shfl_xor(mx, 1));
      mx = fmaxf(mx, __shfl_xor(mx, 2));
      mx = fmaxf(mx, __shfl_xor(mx, 4));
      mx = fmaxf(mx, __shfl_xor(mx, 8));
      float mn = fmaxf(mrun[r], mx);
      al[r] = exp2f((mrun[r] - mn) * c1);
      mrun[r] = mn;
      float p0 = (a0 > -1e29f) ? exp2f((a0 - mn) * c1) : 0.f;
      float p1 = (a1 > -1e29f) ? exp2f((a1 - mn) * c1) : 0.f;
      float sm = p0 + p1;
      sm += __shfl_xor(sm, 1); sm += __shfl_xor(sm, 2);
      sm += __shfl_xor(sm, 4); sm += __shfl_xor(sm, 8);
      lrun[r] = lrun[r] * al[r] + sm;
      sP[wave][(lq*4 + r) * 32 + lr]      = f2b(p0);
      sP[wave][(lq*4 + r) * 32 + 16 + lr] = f2b(p1);
    }
#pragma unroll
    for (int r = 0; r < 4; r++){
      o0[r] *= al[r]; o1[r] *= al[r]; o2[r] *= al[r]; o3[r] *= al[r];
    }
    __builtin_amdgcn_s_waitcnt(0xc07f);   // lgkmcnt(0): P writes visible
    u16x8 pf = ld8(&sP[wave][lr * 32 + lq * 8]);
    o0 = MFMA16(pf, ld8(&sVt[(lr)      * 40 + lq * 8]), o0);
    o1 = MFMA16(pf, ld8(&sVt[(16 + lr) * 40 + lq * 8]), o1);
    o2 = MFMA16(pf, ld8(&sVt[(32 + lr) * 40 + lq * 8]), o2);
    o3 = MFMA16(pf, ld8(&sVt[(48 + lr) * 40 + lq * 8]), o3);
  }

  u16* aor = ao + (size_t)(b * 2048 + qt + lq * 4) * 1024 + hh * 64 + lr;
#pragma unroll
  for (int r = 0; r < 4; r++){
    float inv = 1.f / lrun[r];
    u16* p = aor + (size_t)r * 1024;
    p[0]  = f2b(o0[r] * inv);
    p[16] = f2b(o1[r] * inv);
    p[32] = f2b(o2[r] * inv);
    p[48] = f2b(o3[r] * inv);
  }
}

// ---------------------------------------------------------------------------
// Oscillator scan. u fp32 [B,K,T]; tg already sigmoid'ed [B*T,K].
// ---------------------------------------------------------------------------
__global__ __launch_bounds__(256) void scan_k(
    const float* __restrict__ u_t, const float* __restrict__ tg,
    const float* __restrict__ alog, const float* __restrict__ theta,
    u16* __restrict__ z)
{
  const int bk = blockIdx.x;
  const int b = bk >> 5, k = bk & 31;
  const int j = threadIdx.x;
  const float a = 1.f / (1.f + __expf(-alog[k]));
  const float th = theta[k];
  const float wr = a * __cosf(th), wi = a * __sinf(th);
  const float* ubp = u_t + ((size_t)b * 32 + k) * 2048 + j * 8;
  float4 ua = ((const float4*)ubp)[0];
  float4 ub4 = ((const float4*)ubp)[1];
  float ur[8] = {ua.x, ua.y, ua.z, ua.w, ub4.x, ub4.y, ub4.z, ub4.w};
  float sr = 0.f, si = 0.f;
#pragma unroll
  for (int i = 0; i < 8; i++){
    float nr = wr*sr - wi*si + ur[i];
    float ni = wi*sr + wr*si;
    sr = nr; si = ni;
  }
  float w2r = wr*wr - wi*wi, w2i = 2.f*wr*wi;
  float w4r = w2r*w2r - w2i*w2i, w4i = 2.f*w2r*w2i;
  float Ar = w4r*w4r - w4i*w4i, Ai = 2.f*w4r*w4i;   // w^8
  __shared__ float4 sc[256];
  float4 cur; cur.x = Ar; cur.y = Ai; cur.z = sr; cur.w = si;
  sc[j] = cur;
  __syncthreads();
  for (int s = 1; s < 256; s <<= 1){
    float4 pv;
    const bool has = (j >= s);
    if (has) pv = sc[j - s];
    __syncthreads();
    if (has){
      float nar = cur.x*pv.x - cur.y*pv.y;
      float nai = cur.x*pv.y + cur.y*pv.x;
      float nbr = cur.x*pv.z - cur.y*pv.w + cur.z;
      float nbi = cur.x*pv.w + cur.y*pv.z + cur.w;
      cur.x = nar; cur.y = nai; cur.z = nbr; cur.w = nbi;
    }
    sc[j] = cur;
    __syncthreads();
  }
  float s_r = 0.f, s_i = 0.f;
  if (j > 0){ float4 pr = sc[j - 1]; s_r = pr.z; s_i = pr.w; }
  const float* tgp = tg + ((size_t)b * 2048 + j * 8) * 32 + k;
  u16* zp = z + ((size_t)b * 2048 + j * 8) * 32 + k;
#pragma unroll
  for (int i = 0; i < 8; i++){
    float nr = wr*s_r - wi*s_i + ur[i];
    float ni = wi*s_r + wr*s_i;
    s_r = nr; s_i = ni;
    zp[(size_t)i * 32] = f2b(s_r * tgp[(size_t)i * 32]);
  }
}

// ---------------------------------------------------------------------------
extern "C" void kernel_launch(void* const* d_in, const int* in_sizes, int n_in,
                              void* d_out, int out_size, void* d_ws, size_t ws_size,
                              hipStream_t stream)
{
  (void)in_sizes; (void)n_in; (void)out_size; (void)ws_size;
  const float* x      = (const float*)d_in[0];
  const float* n1w    = (const float*)d_in[1];
  const float* qkvw   = (const float*)d_in[2];
  const float* qkvb   = (const float*)d_in[3];
  const float* projw  = (const float*)d_in[4];
  const float* projb  = (const float*)d_in[5];
  const float* gatew  = (const float*)d_in[6];
  const float* gateb  = (const float*)d_in[7];
  const float* twin   = (const float*)d_in[8];
  const float* twout  = (const float*)d_in[9];
  const float* tgw    = (const float*)d_in[10];
  const float* tgb    = (const float*)d_in[11];
  const float* talog  = (const float*)d_in[12];
  const float* ttheta = (const float*)d_in[13];
  const float* tscale = (const float*)d_in[14];
  const float* n2w    = (const float*)d_in[15];
  const float* fgw    = (const float*)d_in[16];
  const float* fuw    = (const float*)d_in[17];
  const float* fdw    = (const float*)d_in[18];
  float* out = (float*)d_out;

  char* wsb = (char*)d_ws;
  size_t off = 0;
  auto take = [&](size_t bytes) -> void* {
    void* r = wsb + off; off += (bytes + 255) & ~(size_t)255; return r;
  };
  u16*   wall = (u16*)take(16941056ull * 2);   // packed bf16 weights
  u16*   h    = (u16*)take(4194304ull * 2);
  u16*   h2   = (u16*)take(4194304ull * 2);
  u16*   trn  = (u16*)take(4194304ull * 2);
  float* g    = (float*)take(4096ull * 4);
  float* u_t  = (float*)take(131072ull * 4);   // TRN drive [B,K,T]
  float* tg   = (float*)take(131072ull * 4);   // sigmoid gate [B*T,K]
  u16*   zz   = (u16*)take(131072ull * 2);
  u16*   regA = (u16*)take(4096ull * 4096 * 2);  // qkv -> proj partials
  u16*   regB = (u16*)take(4096ull * 4096 * 2);  // ao  -> act

  u16* wq  = wall;                            // [3200][1024] qkv | trn combined
  u16* wp  = wall + 3276800;
  u16* wgu = wall + 4325376;                  // [8192][1024] group-interleaved
  u16* wd  = wall + 12713984;                 // [1024][4096]
  u16* wo  = wall + 16908288;                 // [1024][32]
  u16*   qkv   = regA;
  float* pproj = (float*)regA;  // 2 x 4096x1024 fp32 (reuses regA after attn)
  u16*   ao    = regB;
  u16*   act   = regB;          // reuses regB after proj GEMM consumed ao

  convert_w<<<16544, 256, 0, stream>>>(qkvw, projw, fgw, fuw, fdw, twin, tgw, twout, wall);
  rmsnorm_gate<<<4096, 256, 0, stream>>>(x, n1w, gatew, gateb, h, g);
  // merged qkv + TRN drive/gate GEMM (N=3200)
  gemm_bt<0, true><<<dim3(32, 25), 256, 0, stream>>>(h, wq, u_t, tg, qkv, qkvb,
                                                     tgb, 0, 3200, 1024);
  attn_win<<<1024, 256, 0, stream>>>(qkv, ao);
  scan_k<<<64, 256, 0, stream>>>(u_t, tg, talog, ttheta, zz);
  gemm_bt<6, false><<<dim3(32, 8), 256, 0, stream>>>(zz, wo, nullptr, nullptr, trn, nullptr,
                                                     tscale, 0, 1024, 32);
  // proj split-K2 -> partials, then fused reduce+mix+rmsnorm2 (writes out=xmid, h2)
  gemm_bt<8, true><<<dim3(32, 8, 2), 256, 0, stream>>>(ao, wp, pproj, nullptr, nullptr, nullptr,
                                                       nullptr, 4194304, 1024, 1024);
  reduce_mix_norm<<<4096, 256, 0, stream>>>(pproj, x, trn, g, projb, n2w, out, h2);
  // FFN: merged gate+up, then down split-K4 atomic into out
  gemm_bt<7, true><<<dim3(32, 64), 256, 0, stream>>>(h2, wgu, nullptr, nullptr, act, nullptr,
                                                     nullptr, 0, 8192, 1024);
  gemm_bt<3, true><<<dim3(32, 8, 4), 256, 0, stream>>>(act, wd, out, nullptr, nullptr, nullptr,
                                                       nullptr, 0, 1024, 4096);
}

// Round 5
// 434.235 us; speedup vs baseline: 1.0915x; 1.0915x over previous
//
#include <hip/hip_runtime.h>

// DualMemoryBlock: rmsnorm -> {windowed attn, oscillator TRN} -> gated mix -> SwiGLU FFN
// bf16 MFMA 16x16x32, 128x128 tile, global_load_lds(16B) staging, BK=64 K-loop.
// R5: down-GEMM back to deterministic split-K2 partials + in-place reduce into out
// (R4's atomicAdd epilogue measured MfmaUtil 15% / 90us -- atomics serialize in L2).

typedef unsigned short u16;
typedef unsigned short u16x8 __attribute__((ext_vector_type(8)));
typedef __bf16 bf16x8 __attribute__((ext_vector_type(8)));
typedef float f32x4 __attribute__((ext_vector_type(4)));

#define DI static __device__ __forceinline__

DI u16 f2b(float f){
  union { float f; unsigned u; } v; v.f = f;
  unsigned r = v.u + 0x7FFFu + ((v.u >> 16) & 1u);
  return (u16)(r >> 16);
}
DI float b2f(u16 b){
  union { unsigned u; float f; } v; v.u = ((unsigned)b) << 16; return v.f;
}
DI u16x8 ld8(const u16* p){ return *(const u16x8*)p; }

DI f32x4 MFMA16(u16x8 a, u16x8 b, f32x4 c){
  return __builtin_amdgcn_mfma_f32_16x16x32_bf16(
      __builtin_bit_cast(bf16x8, a), __builtin_bit_cast(bf16x8, b), c, 0, 0, 0);
}

DI void async16(const void* g, void* l){
  void* gg = const_cast<void*>(g);
  __builtin_amdgcn_global_load_lds(
      (__attribute__((address_space(1))) void*)gg,
      (__attribute__((address_space(3))) void*)l, 16, 0, 0);
}

// ---------------------------------------------------------------------------
// Weight conversion fp32 -> bf16, packed. Element offsets:
//  qkv [3072x1024]                       0 .. 3145728
//  wct [128x1024] win|gate|zeros         3145728 .. 3276800 (adjacent to qkv)
//  proj [1024x1024]                      3276800 .. 4325376
//  gate+up group-interleaved [8192x1024] 4325376 .. 12713984
//  down [1024x4096]                      12713984 .. 16908288
//  wout [1024x32]                        16908288 .. 16941056
// ---------------------------------------------------------------------------
__global__ __launch_bounds__(256) void convert_w(
    const float* __restrict__ qkvw, const float* __restrict__ projw,
    const float* __restrict__ fgw, const float* __restrict__ fuw,
    const float* __restrict__ fdw, const float* __restrict__ twin,
    const float* __restrict__ tgw, const float* __restrict__ twout,
    u16* __restrict__ dst)
{
  size_t i = (size_t)blockIdx.x * 256 + threadIdx.x;
  if (i >= 4235264u) return;
  size_t e = i * 4;
  float4 v;
  if (e < 3145728u)        v = *(const float4*)(qkvw + e);
  else if (e < 3276800u){
    size_t i2 = e - 3145728u;
    int row = (int)(i2 >> 10), c = (int)(i2 & 1023);
    if (row < 32)      v = *(const float4*)(twin + row * 1024 + c);
    else if (row < 64) v = *(const float4*)(tgw + (row - 32) * 1024 + c);
    else               v = make_float4(0.f, 0.f, 0.f, 0.f);
  }
  else if (e < 4325376u)   v = *(const float4*)(projw + (e - 3276800u));
  else if (e < 12713984u){
    size_t i2 = e - 4325376u;
    int row = (int)(i2 >> 10), c = (int)(i2 & 1023);
    int G = row >> 5, j = row & 31;
    const float* src = (j < 16) ? fgw : fuw;
    v = *(const float4*)(src + (size_t)(G * 16 + (j & 15)) * 1024 + c);
  }
  else if (e < 16908288u)  v = *(const float4*)(fdw + (e - 12713984u));
  else                     v = *(const float4*)(twout + (e - 16908288u));
  uint2 p;
  p.x = (unsigned)f2b(v.x) | ((unsigned)f2b(v.y) << 16);
  p.y = (unsigned)f2b(v.z) | ((unsigned)f2b(v.w) << 16);
  *(uint2*)(dst + e) = p;
}

// ---------------------------------------------------------------------------
// RMSNorm (+ fused scalar gate logit for norm1)
// ---------------------------------------------------------------------------
__global__ __launch_bounds__(256) void rmsnorm_gate(
    const float* __restrict__ x, const float* __restrict__ w,
    const float* __restrict__ gw, const float* __restrict__ gb,
    u16* __restrict__ h, float* __restrict__ g)
{
  const int row = blockIdx.x, tid = threadIdx.x;
  const int wave = tid >> 6, lane = tid & 63;
  __shared__ float sb[8];
  float4 xv = ((const float4*)(x + (size_t)row * 1024))[tid];
  float ss = xv.x*xv.x + xv.y*xv.y + xv.z*xv.z + xv.w*xv.w;
#pragma unroll
  for (int m = 32; m; m >>= 1) ss += __shfl_xor(ss, m);
  if (lane == 0) sb[wave] = ss;
  __syncthreads();
  float rstd = rsqrtf((sb[0]+sb[1]+sb[2]+sb[3]) * (1.f/1024.f) + 1e-6f);
  float4 wv = ((const float4*)w)[tid];
  float h0 = xv.x*rstd*wv.x, h1 = xv.y*rstd*wv.y;
  float h2v = xv.z*rstd*wv.z, h3 = xv.w*rstd*wv.w;
  uint2 pk;
  pk.x = (unsigned)f2b(h0) | ((unsigned)f2b(h1) << 16);
  pk.y = (unsigned)f2b(h2v) | ((unsigned)f2b(h3) << 16);
  ((uint2*)(h + (size_t)row * 1024))[tid] = pk;
  float4 gv = ((const float4*)gw)[tid];
  float gd = h0*gv.x + h1*gv.y + h2v*gv.z + h3*gv.w;
#pragma unroll
  for (int m = 32; m; m >>= 1) gd += __shfl_xor(gd, m);
  if (lane == 0) sb[4 + wave] = gd;
  __syncthreads();
  if (tid == 0) g[row] = 1.f / (1.f + __expf(-(sb[4]+sb[5]+sb[6]+sb[7] + gb[0])));
}

// ---------------------------------------------------------------------------
// Fused: proj split-K reduce + bias + gated mix + rmsnorm2.
// out = x + g*(p0+p1+projb) + (1-g)*trn ; h2 = bf16(rms(out)*n2w)
// ---------------------------------------------------------------------------
__global__ __launch_bounds__(256) void reduce_mix_norm(
    const float* __restrict__ part, const float* __restrict__ x,
    const u16* __restrict__ trn, const float* __restrict__ g,
    const float* __restrict__ pb, const float* __restrict__ n2w,
    float* __restrict__ out, u16* __restrict__ h2)
{
  const int row = blockIdx.x, tid = threadIdx.x;
  const int wave = tid >> 6, lane = tid & 63;
  __shared__ float sb[4];
  const size_t ro = (size_t)row * 1024;
  float4 p0 = ((const float4*)(part + ro))[tid];
  float4 p1 = ((const float4*)(part + 4194304 + ro))[tid];
  float4 bb = ((const float4*)pb)[tid];
  float4 xv = ((const float4*)(x + ro))[tid];
  uint2 tz = ((const uint2*)(trn + ro))[tid];
  float gg = g[row];
  float t0 = b2f((u16)tz.x), t1 = b2f((u16)(tz.x >> 16));
  float t2 = b2f((u16)tz.y), t3 = b2f((u16)(tz.y >> 16));
  float m0 = xv.x + gg*(p0.x+p1.x+bb.x) + (1.f-gg)*t0;
  float m1 = xv.y + gg*(p0.y+p1.y+bb.y) + (1.f-gg)*t1;
  float m2 = xv.z + gg*(p0.z+p1.z+bb.z) + (1.f-gg)*t2;
  float m3 = xv.w + gg*(p0.w+p1.w+bb.w) + (1.f-gg)*t3;
  float4 mo; mo.x = m0; mo.y = m1; mo.z = m2; mo.w = m3;
  ((float4*)(out + ro))[tid] = mo;
  float ss = m0*m0 + m1*m1 + m2*m2 + m3*m3;
#pragma unroll
  for (int m = 32; m; m >>= 1) ss += __shfl_xor(ss, m);
  if (lane == 0) sb[wave] = ss;
  __syncthreads();
  float rstd = rsqrtf((sb[0]+sb[1]+sb[2]+sb[3]) * (1.f/1024.f) + 1e-6f);
  float4 wv = ((const float4*)n2w)[tid];
  uint2 pk;
  pk.x = (unsigned)f2b(m0*rstd*wv.x) | ((unsigned)f2b(m1*rstd*wv.y) << 16);
  pk.y = (unsigned)f2b(m2*rstd*wv.z) | ((unsigned)f2b(m3*rstd*wv.w) << 16);
  ((uint2*)(h2 + ro))[tid] = pk;
}

// Down split-K reduce, in place: out += p0 + p1 (out holds xmid).
__global__ __launch_bounds__(256) void reduce_down(
    const float* __restrict__ part, float* __restrict__ out)
{
  size_t i = (size_t)blockIdx.x * 256 + threadIdx.x;
  float4 p0 = ((const float4*)part)[i];
  float4 p1 = ((const float4*)(part + 4194304))[i];
  float4 xv = ((float4*)out)[i];
  float4 o;
  o.x = xv.x + p0.x + p1.x; o.y = xv.y + p0.y + p1.y;
  o.z = xv.z + p0.z + p1.z; o.w = xv.w + p0.w + p1.w;
  ((float4*)out)[i] = o;
}

// ---------------------------------------------------------------------------
// GEMM: out[m,n] = sum_k A[m,k]*B[n,k]  (row-major bf16, fp32 accum)
// 128x128 tile, 256 thr = 2x2 waves; split-K via blockIdx.z.
// WIDE: BK=64 via two 128x32 LDS buffer pairs (one barrier pair per 64-K).
// MODE epilogues:
//  0: n0<3072 -> qkv bf16 + bias (stride 3072);
//     n0==3072 -> TRN drive: c2<32 u[b,k,t]=v; c2<64 tg=sigmoid(v+tgb)
//  6: outB = bf16(v * auxF[0])                            (trn_out, res_scale)
//  7: grouped gate/up: silu(acc[.][2p])*acc[.][2p+1]
//  8: partial fp32 store at z*M + rr*N + col              (split-K partials)
// ---------------------------------------------------------------------------
template<int MODE, bool WIDE>
__global__ __launch_bounds__(256) void gemm_bt(
    const u16* __restrict__ A, const u16* __restrict__ B,
    float* __restrict__ outF, float* __restrict__ outF2, u16* __restrict__ outB,
    const float* __restrict__ bias, const float* __restrict__ auxF,
    int M, int N, int K)
{
  __shared__ __align__(16) u16 sA[2][128 * 32];
  __shared__ __align__(16) u16 sB[2][128 * 32];
  const int tid = threadIdx.x;
  const int wave = tid >> 6, lane = tid & 63;
  const int lr = lane & 15, lq = lane >> 4;
  const int m0 = blockIdx.x * 128, n0 = blockIdx.y * 128;
  const int wm = (wave & 1) * 64, wn = (wave >> 1) * 64;
  const int ks = K / (int)gridDim.z;
  const int kbeg = (int)blockIdx.z * ks, kend = kbeg + ks;
  f32x4 acc[4][4] = {};
  const int srow = wave * 16 + (lane >> 2);
  const int scol = (lane & 3) * 8;
  const u16* gA = A + (size_t)(m0 + srow) * K + scol;
  const u16* gB = B + (size_t)(n0 + srow) * K + scol;
  u16* lA0 = &sA[0][(wave * 16) * 32];
  u16* lA1 = &sA[0][(64 + wave * 16) * 32];
  u16* lB0 = &sB[0][(wave * 16) * 32];
  u16* lB1 = &sB[0][(64 + wave * 16) * 32];
  const size_t K64 = (size_t)64 * K;
  const int BUF = 128 * 32;

  if (WIDE){
    for (int k0 = kbeg; k0 < kend; k0 += 64){
      async16(gA + k0,            lA0);
      async16(gA + K64 + k0,      lA1);
      async16(gB + k0,            lB0);
      async16(gB + K64 + k0,      lB1);
      async16(gA + k0 + 32,       lA0 + BUF);
      async16(gA + K64 + k0 + 32, lA1 + BUF);
      async16(gB + k0 + 32,       lB0 + BUF);
      async16(gB + K64 + k0 + 32, lB1 + BUF);
      __syncthreads();
      u16x8 af[4], bf[4];
#pragma unroll
      for (int i = 0; i < 4; i++) af[i] = ld8(&sA[0][(wm + i*16 + lr)*32 + lq*8]);
#pragma unroll
      for (int i = 0; i < 4; i++) bf[i] = ld8(&sB[0][(wn + i*16 + lr)*32 + lq*8]);
#pragma unroll
      for (int mi = 0; mi < 4; mi++)
#pragma unroll
        for (int ni = 0; ni < 4; ni++)
          acc[mi][ni] = MFMA16(af[mi], bf[ni], acc[mi][ni]);
#pragma unroll
      for (int i = 0; i < 4; i++) af[i] = ld8(&sA[1][(wm + i*16 + lr)*32 + lq*8]);
#pragma unroll
      for (int i = 0; i < 4; i++) bf[i] = ld8(&sB[1][(wn + i*16 + lr)*32 + lq*8]);
#pragma unroll
      for (int mi = 0; mi < 4; mi++)
#pragma unroll
        for (int ni = 0; ni < 4; ni++)
          acc[mi][ni] = MFMA16(af[mi], bf[ni], acc[mi][ni]);
      __syncthreads();
    }
  } else {
    for (int k0 = kbeg; k0 < kend; k0 += 32){
      async16(gA + k0,       lA0);
      async16(gA + K64 + k0, lA1);
      async16(gB + k0,       lB0);
      async16(gB + K64 + k0, lB1);
      __syncthreads();
      u16x8 af[4], bf[4];
#pragma unroll
      for (int i = 0; i < 4; i++) af[i] = ld8(&sA[0][(wm + i*16 + lr)*32 + lq*8]);
#pragma unroll
      for (int i = 0; i < 4; i++) bf[i] = ld8(&sB[0][(wn + i*16 + lr)*32 + lq*8]);
#pragma unroll
      for (int mi = 0; mi < 4; mi++)
#pragma unroll
        for (int ni = 0; ni < 4; ni++)
          acc[mi][ni] = MFMA16(af[mi], bf[ni], acc[mi][ni]);
      __syncthreads();
    }
  }

  if (MODE == 7){
    const int cb = ((n0 + wn) >> 1) + lr;   // packed col base
#pragma unroll
    for (int mi = 0; mi < 4; mi++){
      const int row = m0 + wm + mi*16 + lq*4;
#pragma unroll
      for (int p = 0; p < 2; p++){
        const int col = cb + p*16;
#pragma unroll
        for (int r = 0; r < 4; r++){
          float gv = acc[mi][2*p][r], uv = acc[mi][2*p+1][r];
          float rv = gv / (1.f + __expf(-gv)) * uv;
          outB[(size_t)(row + r) * (N >> 1) + col] = f2b(rv);
        }
      }
    }
    return;
  }

  float scale6 = 0.f;
  if (MODE == 6) scale6 = auxF[0];

#pragma unroll
  for (int mi = 0; mi < 4; mi++){
    const int row = m0 + wm + mi*16 + lq*4;
#pragma unroll
    for (int ni = 0; ni < 4; ni++){
      const int col = n0 + wn + ni*16 + lr;
#pragma unroll
      for (int r = 0; r < 4; r++){
        const int rr = row + r;
        float v = acc[mi][ni][r];
        if (MODE == 0){
          if (n0 < 3072){
            outB[(size_t)rr * 3072 + col] = f2b(v + bias[col]);
          } else {
            int c2 = col - 3072;
            int bb = rr >> 11, tt = rr & 2047;
            if (c2 < 32) outF[((size_t)bb * 32 + c2) * 2048 + tt] = v;
            else if (c2 < 64)
              outF2[(size_t)rr * 32 + (c2 - 32)] =
                  1.f / (1.f + __expf(-(v + auxF[c2 - 32])));
          }
        } else if (MODE == 6){
          outB[(size_t)rr * N + col] = f2b(v * scale6);
        } else if (MODE == 8){
          outF[(size_t)blockIdx.z * (size_t)M + (size_t)rr * N + col] = v;
        }
      }
    }
  }
}

// ---------------------------------------------------------------------------
// Windowed causal flash attention. qkv: [B*T, 3072] bf16 (q|k|v, 16 heads x 64).
// ---------------------------------------------------------------------------
__global__ __launch_bounds__(256) void attn_win(
    const u16* __restrict__ qkv, u16* __restrict__ ao)
{
  const int blk = blockIdx.x;
  const int tile = blk & 31, hh = (blk >> 5) & 15, b = blk >> 9;
  const int t0 = tile * 64;
  const int tid = threadIdx.x, wave = tid >> 6, lane = tid & 63;
  const int lr = lane & 15, lq = lane >> 4;
  const int qt = t0 + wave * 16;
  __shared__ __align__(16) u16 sVt[64 * 40];      // V^T, padded stride 40
  __shared__ __align__(16) u16 sP[4][16 * 32];    // per-wave P buffer

  const u16* base = qkv + (size_t)b * 2048 * 3072 + hh * 64;
  const u16* qrow = base + (size_t)(qt + lr) * 3072 + lq * 8;
  u16x8 qf0 = ld8(qrow), qf1 = ld8(qrow + 32);
  const u16* kbase = base + 1024;
  const u16* vbase = base + 2048;

  f32x4 o0 = {0,0,0,0}, o1 = {0,0,0,0}, o2 = {0,0,0,0}, o3 = {0,0,0,0};
  float mrun[4] = {-1e30f, -1e30f, -1e30f, -1e30f};
  float lrun[4] = {0.f, 0.f, 0.f, 0.f};
  const float c1 = 0.125f * 1.44269504088896f;  // scale * log2(e)

  const int kb = (t0 >= 256) ? (t0 - 256) : 0;
  const int ntl = (t0 + 64 - kb) >> 5;
  for (int it = 0; it < ntl; ++it){
    const int kt = kb + it * 32;
    __syncthreads();                 // prev-iter LDS reads done
    {                                // stage V^T (32 keys x 64 dims), all 256 thr
      const int key = tid & 31, dseg = tid >> 5;
      const u16* gv = vbase + (size_t)(kt + key) * 3072 + dseg * 8;
      u16x8 v0 = ld8(gv);
#pragma unroll
      for (int j = 0; j < 8; j++)
        sVt[(dseg*8 + j) * 40 + key] = v0[j];
    }
    __syncthreads();
    const bool active = (kt < qt + 16) && (kt + 286 >= qt);
    if (!active) continue;           // both barriers are above: counts stay equal

    f32x4 s0 = {0,0,0,0}, s1 = {0,0,0,0};
    {
      const u16* kr = kbase + (size_t)(kt + lr) * 3072 + lq * 8;
      u16x8 k00 = ld8(kr), k01 = ld8(kr + 32);
      const u16* kr1 = kr + (size_t)16 * 3072;
      u16x8 k10 = ld8(kr1), k11 = ld8(kr1 + 32);
      s0 = MFMA16(qf0, k00, s0); s0 = MFMA16(qf1, k01, s0);
      s1 = MFMA16(qf0, k10, s1); s1 = MFMA16(qf1, k11, s1);
    }
    float al[4];
#pragma unroll
    for (int r = 0; r < 4; r++){
      const int q = qt + lq * 4 + r;
      const int ca = kt + lr, cb = kt + 16 + lr;
      float a0 = (ca <= q && ca + 255 >= q) ? s0[r] : -1e30f;
      float a1 = (cb <= q && cb + 255 >= q) ? s1[r] : -1e30f;
      float mx = fmaxf(a0, a1);
      mx = fmaxf(mx, __shfl_xor(mx, 1));
      mx = fmaxf(mx, __shfl_xor(mx, 2));
      mx = fmaxf(mx, __shfl_xor(mx, 4));
      mx = fmaxf(mx, __shfl_xor(mx, 8));
      float mn = fmaxf(mrun[r], mx);
      al[r] = exp2f((mrun[r] - mn) * c1);
      mrun[r] = mn;
      float p0 = (a0 > -1e29f) ? exp2f((a0 - mn) * c1) : 0.f;
      float p1 = (a1 > -1e29f) ? exp2f((a1 - mn) * c1) : 0.f;
      float sm = p0 + p1;
      sm += __shfl_xor(sm, 1); sm += __shfl_xor(sm, 2);
      sm += __shfl_xor(sm, 4); sm += __shfl_xor(sm, 8);
      lrun[r] = lrun[r] * al[r] + sm;
      sP[wave][(lq*4 + r) * 32 + lr]      = f2b(p0);
      sP[wave][(lq*4 + r) * 32 + 16 + lr] = f2b(p1);
    }
#pragma unroll
    for (int r = 0; r < 4; r++){
      o0[r] *= al[r]; o1[r] *= al[r]; o2[r] *= al[r]; o3[r] *= al[r];
    }
    __builtin_amdgcn_s_waitcnt(0xc07f);   // lgkmcnt(0): P writes visible
    u16x8 pf = ld8(&sP[wave][lr * 32 + lq * 8]);
    o0 = MFMA16(pf, ld8(&sVt[(lr)      * 40 + lq * 8]), o0);
    o1 = MFMA16(pf, ld8(&sVt[(16 + lr) * 40 + lq * 8]), o1);
    o2 = MFMA16(pf, ld8(&sVt[(32 + lr) * 40 + lq * 8]), o2);
    o3 = MFMA16(pf, ld8(&sVt[(48 + lr) * 40 + lq * 8]), o3);
  }

  u16* aor = ao + (size_t)(b * 2048 + qt + lq * 4) * 1024 + hh * 64 + lr;
#pragma unroll
  for (int r = 0; r < 4; r++){
    float inv = 1.f / lrun[r];
    u16* p = aor + (size_t)r * 1024;
    p[0]  = f2b(o0[r] * inv);
    p[16] = f2b(o1[r] * inv);
    p[32] = f2b(o2[r] * inv);
    p[48] = f2b(o3[r] * inv);
  }
}

// ---------------------------------------------------------------------------
// Oscillator scan. u fp32 [B,K,T]; tg already sigmoid'ed [B*T,K].
// ---------------------------------------------------------------------------
__global__ __launch_bounds__(256) void scan_k(
    const float* __restrict__ u_t, const float* __restrict__ tg,
    const float* __restrict__ alog, const float* __restrict__ theta,
    u16* __restrict__ z)
{
  const int bk = blockIdx.x;
  const int b = bk >> 5, k = bk & 31;
  const int j = threadIdx.x;
  const float a = 1.f / (1.f + __expf(-alog[k]));
  const float th = theta[k];
  const float wr = a * __cosf(th), wi = a * __sinf(th);
  const float* ubp = u_t + ((size_t)b * 32 + k) * 2048 + j * 8;
  float4 ua = ((const float4*)ubp)[0];
  float4 ub4 = ((const float4*)ubp)[1];
  float ur[8] = {ua.x, ua.y, ua.z, ua.w, ub4.x, ub4.y, ub4.z, ub4.w};
  float sr = 0.f, si = 0.f;
#pragma unroll
  for (int i = 0; i < 8; i++){
    float nr = wr*sr - wi*si + ur[i];
    float ni = wi*sr + wr*si;
    sr = nr; si = ni;
  }
  float w2r = wr*wr - wi*wi, w2i = 2.f*wr*wi;
  float w4r = w2r*w2r - w2i*w2i, w4i = 2.f*w2r*w2i;
  float Ar = w4r*w4r - w4i*w4i, Ai = 2.f*w4r*w4i;   // w^8
  __shared__ float4 sc[256];
  float4 cur; cur.x = Ar; cur.y = Ai; cur.z = sr; cur.w = si;
  sc[j] = cur;
  __syncthreads();
  for (int s = 1; s < 256; s <<= 1){
    float4 pv;
    const bool has = (j >= s);
    if (has) pv = sc[j - s];
    __syncthreads();
    if (has){
      float nar = cur.x*pv.x - cur.y*pv.y;
      float nai = cur.x*pv.y + cur.y*pv.x;
      float nbr = cur.x*pv.z - cur.y*pv.w + cur.z;
      float nbi = cur.x*pv.w + cur.y*pv.z + cur.w;
      cur.x = nar; cur.y = nai; cur.z = nbr; cur.w = nbi;
    }
    sc[j] = cur;
    __syncthreads();
  }
  float s_r = 0.f, s_i = 0.f;
  if (j > 0){ float4 pr = sc[j - 1]; s_r = pr.z; s_i = pr.w; }
  const float* tgp = tg + ((size_t)b * 2048 + j * 8) * 32 + k;
  u16* zp = z + ((size_t)b * 2048 + j * 8) * 32 + k;
#pragma unroll
  for (int i = 0; i < 8; i++){
    float nr = wr*s_r - wi*s_i + ur[i];
    float ni = wi*s_r + wr*s_i;
    s_r = nr; s_i = ni;
    zp[(size_t)i * 32] = f2b(s_r * tgp[(size_t)i * 32]);
  }
}

// ---------------------------------------------------------------------------
extern "C" void kernel_launch(void* const* d_in, const int* in_sizes, int n_in,
                              void* d_out, int out_size, void* d_ws, size_t ws_size,
                              hipStream_t stream)
{
  (void)in_sizes; (void)n_in; (void)out_size; (void)ws_size;
  const float* x      = (const float*)d_in[0];
  const float* n1w    = (const float*)d_in[1];
  const float* qkvw   = (const float*)d_in[2];
  const float* qkvb   = (const float*)d_in[3];
  const float* projw  = (const float*)d_in[4];
  const float* projb  = (const float*)d_in[5];
  const float* gatew  = (const float*)d_in[6];
  const float* gateb  = (const float*)d_in[7];
  const float* twin   = (const float*)d_in[8];
  const float* twout  = (const float*)d_in[9];
  const float* tgw    = (const float*)d_in[10];
  const float* tgb    = (const float*)d_in[11];
  const float* talog  = (const float*)d_in[12];
  const float* ttheta = (const float*)d_in[13];
  const float* tscale = (const float*)d_in[14];
  const float* n2w    = (const float*)d_in[15];
  const float* fgw    = (const float*)d_in[16];
  const float* fuw    = (const float*)d_in[17];
  const float* fdw    = (const float*)d_in[18];
  float* out = (float*)d_out;

  char* wsb = (char*)d_ws;
  size_t off = 0;
  auto take = [&](size_t bytes) -> void* {
    void* r = wsb + off; off += (bytes + 255) & ~(size_t)255; return r;
  };
  u16*   wall = (u16*)take(16941056ull * 2);   // packed bf16 weights
  u16*   h    = (u16*)take(4194304ull * 2);
  u16*   h2   = (u16*)take(4194304ull * 2);
  u16*   trn  = (u16*)take(4194304ull * 2);
  float* g    = (float*)take(4096ull * 4);
  float* u_t  = (float*)take(131072ull * 4);   // TRN drive [B,K,T]
  float* tg   = (float*)take(131072ull * 4);   // sigmoid gate [B*T,K]
  u16*   zz   = (u16*)take(131072ull * 2);
  u16*   regA = (u16*)take(4096ull * 4096 * 2);  // qkv -> proj partials -> down partials
  u16*   regB = (u16*)take(4096ull * 4096 * 2);  // ao  -> act

  u16* wq  = wall;                            // [3200][1024] qkv | trn combined
  u16* wp  = wall + 3276800;
  u16* wgu = wall + 4325376;                  // [8192][1024] group-interleaved
  u16* wd  = wall + 12713984;                 // [1024][4096]
  u16* wo  = wall + 16908288;                 // [1024][32]
  u16*   qkv   = regA;
  float* pproj = (float*)regA;  // 2 x 4096x1024 fp32 (reuses regA after attn)
  float* pdown = (float*)regA;  // reuses regA again after reduce_mix_norm
  u16*   ao    = regB;
  u16*   act   = regB;          // reuses regB after proj GEMM consumed ao

  convert_w<<<16544, 256, 0, stream>>>(qkvw, projw, fgw, fuw, fdw, twin, tgw, twout, wall);
  rmsnorm_gate<<<4096, 256, 0, stream>>>(x, n1w, gatew, gateb, h, g);
  // merged qkv + TRN drive/gate GEMM (N=3200)
  gemm_bt<0, true><<<dim3(32, 25), 256, 0, stream>>>(h, wq, u_t, tg, qkv, qkvb,
                                                     tgb, 0, 3200, 1024);
  attn_win<<<1024, 256, 0, stream>>>(qkv, ao);
  scan_k<<<64, 256, 0, stream>>>(u_t, tg, talog, ttheta, zz);
  gemm_bt<6, false><<<dim3(32, 8), 256, 0, stream>>>(zz, wo, nullptr, nullptr, trn, nullptr,
                                                     tscale, 0, 1024, 32);
  // proj split-K2 -> partials, then fused reduce+mix+rmsnorm2 (writes out=xmid, h2)
  gemm_bt<8, true><<<dim3(32, 8, 2), 256, 0, stream>>>(ao, wp, pproj, nullptr, nullptr, nullptr,
                                                       nullptr, 4194304, 1024, 1024);
  reduce_mix_norm<<<4096, 256, 0, stream>>>(pproj, x, trn, g, projb, n2w, out, h2);
  // FFN: merged gate+up, then down split-K2 -> partials, in-place reduce into out
  gemm_bt<7, true><<<dim3(32, 64), 256, 0, stream>>>(h2, wgu, nullptr, nullptr, act, nullptr,
                                                     nullptr, 0, 8192, 1024);
  gemm_bt<8, true><<<dim3(32, 8, 2), 256, 0, stream>>>(act, wd, pdown, nullptr, nullptr, nullptr,
                                                       nullptr, 4194304, 1024, 4096);
  reduce_down<<<4096, 256, 0, stream>>>(pdown, out);
}

// Round 6
// 418.497 us; speedup vs baseline: 1.1325x; 1.0376x over previous
//
#include <hip/hip_runtime.h>

// DualMemoryBlock: rmsnorm -> {windowed attn, oscillator TRN} -> gated mix -> SwiGLU FFN
// bf16 MFMA 16x16x32, 128x128 tile, global_load_lds(16B) staging, BK=64 K-loop.
// R6: attention without online-max (scores provably small; lane-local l-sum,
// one final shuffle-reduce) -- kills 32 shfl + rescale per 32-key tile.
// Split-K partials stored as bf16 (halves partial traffic; 0.4% rounding, safe).

typedef unsigned short u16;
typedef unsigned short u16x8 __attribute__((ext_vector_type(8)));
typedef __bf16 bf16x8 __attribute__((ext_vector_type(8)));
typedef float f32x4 __attribute__((ext_vector_type(4)));

#define DI static __device__ __forceinline__

DI u16 f2b(float f){
  union { float f; unsigned u; } v; v.f = f;
  unsigned r = v.u + 0x7FFFu + ((v.u >> 16) & 1u);
  return (u16)(r >> 16);
}
DI float b2f(u16 b){
  union { unsigned u; float f; } v; v.u = ((unsigned)b) << 16; return v.f;
}
DI u16x8 ld8(const u16* p){ return *(const u16x8*)p; }

DI f32x4 MFMA16(u16x8 a, u16x8 b, f32x4 c){
  return __builtin_amdgcn_mfma_f32_16x16x32_bf16(
      __builtin_bit_cast(bf16x8, a), __builtin_bit_cast(bf16x8, b), c, 0, 0, 0);
}

DI void async16(const void* g, void* l){
  void* gg = const_cast<void*>(g);
  __builtin_amdgcn_global_load_lds(
      (__attribute__((address_space(1))) void*)gg,
      (__attribute__((address_space(3))) void*)l, 16, 0, 0);
}

// ---------------------------------------------------------------------------
// Weight conversion fp32 -> bf16, packed. Element offsets:
//  qkv [3072x1024]                       0 .. 3145728
//  wct [128x1024] win|gate|zeros         3145728 .. 3276800 (adjacent to qkv)
//  proj [1024x1024]                      3276800 .. 4325376
//  gate+up group-interleaved [8192x1024] 4325376 .. 12713984
//  down [1024x4096]                      12713984 .. 16908288
//  wout [1024x32]                        16908288 .. 16941056
// ---------------------------------------------------------------------------
__global__ __launch_bounds__(256) void convert_w(
    const float* __restrict__ qkvw, const float* __restrict__ projw,
    const float* __restrict__ fgw, const float* __restrict__ fuw,
    const float* __restrict__ fdw, const float* __restrict__ twin,
    const float* __restrict__ tgw, const float* __restrict__ twout,
    u16* __restrict__ dst)
{
  size_t i = (size_t)blockIdx.x * 256 + threadIdx.x;
  if (i >= 4235264u) return;
  size_t e = i * 4;
  float4 v;
  if (e < 3145728u)        v = *(const float4*)(qkvw + e);
  else if (e < 3276800u){
    size_t i2 = e - 3145728u;
    int row = (int)(i2 >> 10), c = (int)(i2 & 1023);
    if (row < 32)      v = *(const float4*)(twin + row * 1024 + c);
    else if (row < 64) v = *(const float4*)(tgw + (row - 32) * 1024 + c);
    else               v = make_float4(0.f, 0.f, 0.f, 0.f);
  }
  else if (e < 4325376u)   v = *(const float4*)(projw + (e - 3276800u));
  else if (e < 12713984u){
    size_t i2 = e - 4325376u;
    int row = (int)(i2 >> 10), c = (int)(i2 & 1023);
    int G = row >> 5, j = row & 31;
    const float* src = (j < 16) ? fgw : fuw;
    v = *(const float4*)(src + (size_t)(G * 16 + (j & 15)) * 1024 + c);
  }
  else if (e < 16908288u)  v = *(const float4*)(fdw + (e - 12713984u));
  else                     v = *(const float4*)(twout + (e - 16908288u));
  uint2 p;
  p.x = (unsigned)f2b(v.x) | ((unsigned)f2b(v.y) << 16);
  p.y = (unsigned)f2b(v.z) | ((unsigned)f2b(v.w) << 16);
  *(uint2*)(dst + e) = p;
}

// ---------------------------------------------------------------------------
// RMSNorm (+ fused scalar gate logit for norm1)
// ---------------------------------------------------------------------------
__global__ __launch_bounds__(256) void rmsnorm_gate(
    const float* __restrict__ x, const float* __restrict__ w,
    const float* __restrict__ gw, const float* __restrict__ gb,
    u16* __restrict__ h, float* __restrict__ g)
{
  const int row = blockIdx.x, tid = threadIdx.x;
  const int wave = tid >> 6, lane = tid & 63;
  __shared__ float sb[8];
  float4 xv = ((const float4*)(x + (size_t)row * 1024))[tid];
  float ss = xv.x*xv.x + xv.y*xv.y + xv.z*xv.z + xv.w*xv.w;
#pragma unroll
  for (int m = 32; m; m >>= 1) ss += __shfl_xor(ss, m);
  if (lane == 0) sb[wave] = ss;
  __syncthreads();
  float rstd = rsqrtf((sb[0]+sb[1]+sb[2]+sb[3]) * (1.f/1024.f) + 1e-6f);
  float4 wv = ((const float4*)w)[tid];
  float h0 = xv.x*rstd*wv.x, h1 = xv.y*rstd*wv.y;
  float h2v = xv.z*rstd*wv.z, h3 = xv.w*rstd*wv.w;
  uint2 pk;
  pk.x = (unsigned)f2b(h0) | ((unsigned)f2b(h1) << 16);
  pk.y = (unsigned)f2b(h2v) | ((unsigned)f2b(h3) << 16);
  ((uint2*)(h + (size_t)row * 1024))[tid] = pk;
  float4 gv = ((const float4*)gw)[tid];
  float gd = h0*gv.x + h1*gv.y + h2v*gv.z + h3*gv.w;
#pragma unroll
  for (int m = 32; m; m >>= 1) gd += __shfl_xor(gd, m);
  if (lane == 0) sb[4 + wave] = gd;
  __syncthreads();
  if (tid == 0) g[row] = 1.f / (1.f + __expf(-(sb[4]+sb[5]+sb[6]+sb[7] + gb[0])));
}

// ---------------------------------------------------------------------------
// Fused: proj split-K reduce (bf16 partials) + bias + gated mix + rmsnorm2.
// out = x + g*(p0+p1+projb) + (1-g)*trn ; h2 = bf16(rms(out)*n2w)
// ---------------------------------------------------------------------------
__global__ __launch_bounds__(256) void reduce_mix_norm(
    const u16* __restrict__ part, const float* __restrict__ x,
    const u16* __restrict__ trn, const float* __restrict__ g,
    const float* __restrict__ pb, const float* __restrict__ n2w,
    float* __restrict__ out, u16* __restrict__ h2)
{
  const int row = blockIdx.x, tid = threadIdx.x;
  const int wave = tid >> 6, lane = tid & 63;
  __shared__ float sb[4];
  const size_t ro = (size_t)row * 1024;
  uint2 a0 = ((const uint2*)(part + ro))[tid];
  uint2 a1 = ((const uint2*)(part + 4194304 + ro))[tid];
  float4 bb = ((const float4*)pb)[tid];
  float4 xv = ((const float4*)(x + ro))[tid];
  uint2 tz = ((const uint2*)(trn + ro))[tid];
  float gg = g[row];
  float p00 = b2f((u16)a0.x), p01 = b2f((u16)(a0.x >> 16));
  float p02 = b2f((u16)a0.y), p03 = b2f((u16)(a0.y >> 16));
  float p10 = b2f((u16)a1.x), p11 = b2f((u16)(a1.x >> 16));
  float p12 = b2f((u16)a1.y), p13 = b2f((u16)(a1.y >> 16));
  float t0 = b2f((u16)tz.x), t1 = b2f((u16)(tz.x >> 16));
  float t2 = b2f((u16)tz.y), t3 = b2f((u16)(tz.y >> 16));
  float m0 = xv.x + gg*(p00+p10+bb.x) + (1.f-gg)*t0;
  float m1 = xv.y + gg*(p01+p11+bb.y) + (1.f-gg)*t1;
  float m2 = xv.z + gg*(p02+p12+bb.z) + (1.f-gg)*t2;
  float m3 = xv.w + gg*(p03+p13+bb.w) + (1.f-gg)*t3;
  float4 mo; mo.x = m0; mo.y = m1; mo.z = m2; mo.w = m3;
  ((float4*)(out + ro))[tid] = mo;
  float ss = m0*m0 + m1*m1 + m2*m2 + m3*m3;
#pragma unroll
  for (int m = 32; m; m >>= 1) ss += __shfl_xor(ss, m);
  if (lane == 0) sb[wave] = ss;
  __syncthreads();
  float rstd = rsqrtf((sb[0]+sb[1]+sb[2]+sb[3]) * (1.f/1024.f) + 1e-6f);
  float4 wv = ((const float4*)n2w)[tid];
  uint2 pk;
  pk.x = (unsigned)f2b(m0*rstd*wv.x) | ((unsigned)f2b(m1*rstd*wv.y) << 16);
  pk.y = (unsigned)f2b(m2*rstd*wv.z) | ((unsigned)f2b(m3*rstd*wv.w) << 16);
  ((uint2*)(h2 + ro))[tid] = pk;
}

// Down split-K reduce, in place: out += p0 + p1 (bf16 partials; out holds xmid).
__global__ __launch_bounds__(256) void reduce_down(
    const u16* __restrict__ part, float* __restrict__ out)
{
  size_t i = (size_t)blockIdx.x * 256 + threadIdx.x;
  uint2 a0 = ((const uint2*)part)[i];
  uint2 a1 = ((const uint2*)(part + 4194304))[i];
  float4 xv = ((float4*)out)[i];
  float4 o;
  o.x = xv.x + b2f((u16)a0.x) + b2f((u16)a1.x);
  o.y = xv.y + b2f((u16)(a0.x >> 16)) + b2f((u16)(a1.x >> 16));
  o.z = xv.z + b2f((u16)a0.y) + b2f((u16)a1.y);
  o.w = xv.w + b2f((u16)(a0.y >> 16)) + b2f((u16)(a1.y >> 16));
  ((float4*)out)[i] = o;
}

// ---------------------------------------------------------------------------
// GEMM: out[m,n] = sum_k A[m,k]*B[n,k]  (row-major bf16, fp32 accum)
// 128x128 tile, 256 thr = 2x2 waves; split-K via blockIdx.z.
// WIDE: BK=64 via two 128x32 LDS buffer pairs (one barrier pair per 64-K).
// MODE epilogues:
//  0: n0<3072 -> qkv bf16 + bias (stride 3072);
//     n0==3072 -> TRN drive: c2<32 u[b,k,t]=v; c2<64 tg=sigmoid(v+tgb)
//  6: outB = bf16(v * auxF[0])                            (trn_out, res_scale)
//  7: grouped gate/up: silu(acc[.][2p])*acc[.][2p+1]
//  9: bf16 partial store at z*M + rr*N + col              (split-K partials)
// ---------------------------------------------------------------------------
template<int MODE, bool WIDE>
__global__ __launch_bounds__(256) void gemm_bt(
    const u16* __restrict__ A, const u16* __restrict__ B,
    float* __restrict__ outF, float* __restrict__ outF2, u16* __restrict__ outB,
    const float* __restrict__ bias, const float* __restrict__ auxF,
    int M, int N, int K)
{
  __shared__ __align__(16) u16 sA[2][128 * 32];
  __shared__ __align__(16) u16 sB[2][128 * 32];
  const int tid = threadIdx.x;
  const int wave = tid >> 6, lane = tid & 63;
  const int lr = lane & 15, lq = lane >> 4;
  const int m0 = blockIdx.x * 128, n0 = blockIdx.y * 128;
  const int wm = (wave & 1) * 64, wn = (wave >> 1) * 64;
  const int ks = K / (int)gridDim.z;
  const int kbeg = (int)blockIdx.z * ks, kend = kbeg + ks;
  f32x4 acc[4][4] = {};
  const int srow = wave * 16 + (lane >> 2);
  const int scol = (lane & 3) * 8;
  const u16* gA = A + (size_t)(m0 + srow) * K + scol;
  const u16* gB = B + (size_t)(n0 + srow) * K + scol;
  u16* lA0 = &sA[0][(wave * 16) * 32];
  u16* lA1 = &sA[0][(64 + wave * 16) * 32];
  u16* lB0 = &sB[0][(wave * 16) * 32];
  u16* lB1 = &sB[0][(64 + wave * 16) * 32];
  const size_t K64 = (size_t)64 * K;
  const int BUF = 128 * 32;

  if (WIDE){
    for (int k0 = kbeg; k0 < kend; k0 += 64){
      async16(gA + k0,            lA0);
      async16(gA + K64 + k0,      lA1);
      async16(gB + k0,            lB0);
      async16(gB + K64 + k0,      lB1);
      async16(gA + k0 + 32,       lA0 + BUF);
      async16(gA + K64 + k0 + 32, lA1 + BUF);
      async16(gB + k0 + 32,       lB0 + BUF);
      async16(gB + K64 + k0 + 32, lB1 + BUF);
      __syncthreads();
      u16x8 af[4], bf[4];
#pragma unroll
      for (int i = 0; i < 4; i++) af[i] = ld8(&sA[0][(wm + i*16 + lr)*32 + lq*8]);
#pragma unroll
      for (int i = 0; i < 4; i++) bf[i] = ld8(&sB[0][(wn + i*16 + lr)*32 + lq*8]);
#pragma unroll
      for (int mi = 0; mi < 4; mi++)
#pragma unroll
        for (int ni = 0; ni < 4; ni++)
          acc[mi][ni] = MFMA16(af[mi], bf[ni], acc[mi][ni]);
#pragma unroll
      for (int i = 0; i < 4; i++) af[i] = ld8(&sA[1][(wm + i*16 + lr)*32 + lq*8]);
#pragma unroll
      for (int i = 0; i < 4; i++) bf[i] = ld8(&sB[1][(wn + i*16 + lr)*32 + lq*8]);
#pragma unroll
      for (int mi = 0; mi < 4; mi++)
#pragma unroll
        for (int ni = 0; ni < 4; ni++)
          acc[mi][ni] = MFMA16(af[mi], bf[ni], acc[mi][ni]);
      __syncthreads();
    }
  } else {
    for (int k0 = kbeg; k0 < kend; k0 += 32){
      async16(gA + k0,       lA0);
      async16(gA + K64 + k0, lA1);
      async16(gB + k0,       lB0);
      async16(gB + K64 + k0, lB1);
      __syncthreads();
      u16x8 af[4], bf[4];
#pragma unroll
      for (int i = 0; i < 4; i++) af[i] = ld8(&sA[0][(wm + i*16 + lr)*32 + lq*8]);
#pragma unroll
      for (int i = 0; i < 4; i++) bf[i] = ld8(&sB[0][(wn + i*16 + lr)*32 + lq*8]);
#pragma unroll
      for (int mi = 0; mi < 4; mi++)
#pragma unroll
        for (int ni = 0; ni < 4; ni++)
          acc[mi][ni] = MFMA16(af[mi], bf[ni], acc[mi][ni]);
      __syncthreads();
    }
  }

  if (MODE == 7){
    const int cb = ((n0 + wn) >> 1) + lr;   // packed col base
#pragma unroll
    for (int mi = 0; mi < 4; mi++){
      const int row = m0 + wm + mi*16 + lq*4;
#pragma unroll
      for (int p = 0; p < 2; p++){
        const int col = cb + p*16;
#pragma unroll
        for (int r = 0; r < 4; r++){
          float gv = acc[mi][2*p][r], uv = acc[mi][2*p+1][r];
          float rv = gv / (1.f + __expf(-gv)) * uv;
          outB[(size_t)(row + r) * (N >> 1) + col] = f2b(rv);
        }
      }
    }
    return;
  }

  float scale6 = 0.f;
  if (MODE == 6) scale6 = auxF[0];

#pragma unroll
  for (int mi = 0; mi < 4; mi++){
    const int row = m0 + wm + mi*16 + lq*4;
#pragma unroll
    for (int ni = 0; ni < 4; ni++){
      const int col = n0 + wn + ni*16 + lr;
#pragma unroll
      for (int r = 0; r < 4; r++){
        const int rr = row + r;
        float v = acc[mi][ni][r];
        if (MODE == 0){
          if (n0 < 3072){
            outB[(size_t)rr * 3072 + col] = f2b(v + bias[col]);
          } else {
            int c2 = col - 3072;
            int bb = rr >> 11, tt = rr & 2047;
            if (c2 < 32) outF[((size_t)bb * 32 + c2) * 2048 + tt] = v;
            else if (c2 < 64)
              outF2[(size_t)rr * 32 + (c2 - 32)] =
                  1.f / (1.f + __expf(-(v + auxF[c2 - 32])));
          }
        } else if (MODE == 6){
          outB[(size_t)rr * N + col] = f2b(v * scale6);
        } else if (MODE == 9){
          outB[(size_t)blockIdx.z * (size_t)M + (size_t)rr * N + col] = f2b(v);
        }
      }
    }
  }
}

// ---------------------------------------------------------------------------
// Windowed causal flash attention, NO online max (scores bounded: |s*c1| < ~15,
// fp32 exp2 range 2^127 -- unnormalized accumulation is safe).
// qkv: [B*T, 3072] bf16 (q|k|v, 16 heads x 64). l summed lane-locally,
// reduced across the 16 row-lanes once at the end.
// ---------------------------------------------------------------------------
__global__ __launch_bounds__(256) void attn_win(
    const u16* __restrict__ qkv, u16* __restrict__ ao)
{
  const int blk = blockIdx.x;
  const int tile = blk & 31, hh = (blk >> 5) & 15, b = blk >> 9;
  const int t0 = tile * 64;
  const int tid = threadIdx.x, wave = tid >> 6, lane = tid & 63;
  const int lr = lane & 15, lq = lane >> 4;
  const int qt = t0 + wave * 16;
  __shared__ __align__(16) u16 sVt[64 * 40];      // V^T, padded stride 40
  __shared__ __align__(16) u16 sP[4][16 * 32];    // per-wave P buffer

  const u16* base = qkv + (size_t)b * 2048 * 3072 + hh * 64;
  const u16* qrow = base + (size_t)(qt + lr) * 3072 + lq * 8;
  u16x8 qf0 = ld8(qrow), qf1 = ld8(qrow + 32);
  const u16* kbase = base + 1024;
  const u16* vbase = base + 2048;

  f32x4 o0 = {0,0,0,0}, o1 = {0,0,0,0}, o2 = {0,0,0,0}, o3 = {0,0,0,0};
  float lsum[4] = {0.f, 0.f, 0.f, 0.f};
  const float c1 = 0.125f * 1.44269504088896f;  // scale * log2(e)

  const int kb = (t0 >= 256) ? (t0 - 256) : 0;
  const int ntl = (t0 + 64 - kb) >> 5;
  for (int it = 0; it < ntl; ++it){
    const int kt = kb + it * 32;
    __syncthreads();                 // prev-iter LDS reads done
    {                                // stage V^T (32 keys x 64 dims), all 256 thr
      const int key = tid & 31, dseg = tid >> 5;
      const u16* gv = vbase + (size_t)(kt + key) * 3072 + dseg * 8;
      u16x8 v0 = ld8(gv);
#pragma unroll
      for (int j = 0; j < 8; j++)
        sVt[(dseg*8 + j) * 40 + key] = v0[j];
    }
    __syncthreads();
    const bool active = (kt < qt + 16) && (kt + 286 >= qt);
    if (!active) continue;           // both barriers are above: counts stay equal

    f32x4 s0 = {0,0,0,0}, s1 = {0,0,0,0};
    {
      const u16* kr = kbase + (size_t)(kt + lr) * 3072 + lq * 8;
      u16x8 k00 = ld8(kr), k01 = ld8(kr + 32);
      const u16* kr1 = kr + (size_t)16 * 3072;
      u16x8 k10 = ld8(kr1), k11 = ld8(kr1 + 32);
      s0 = MFMA16(qf0, k00, s0); s0 = MFMA16(qf1, k01, s0);
      s1 = MFMA16(qf0, k10, s1); s1 = MFMA16(qf1, k11, s1);
    }
#pragma unroll
    for (int r = 0; r < 4; r++){
      const int q = qt + lq * 4 + r;
      const int ca = kt + lr, cb = kt + 16 + lr;
      float p0 = (ca <= q && ca + 255 >= q) ? exp2f(s0[r] * c1) : 0.f;
      float p1 = (cb <= q && cb + 255 >= q) ? exp2f(s1[r] * c1) : 0.f;
      lsum[r] += p0 + p1;
      sP[wave][(lq*4 + r) * 32 + lr]      = f2b(p0);
      sP[wave][(lq*4 + r) * 32 + 16 + lr] = f2b(p1);
    }
    __builtin_amdgcn_s_waitcnt(0xc07f);   // lgkmcnt(0): P writes visible
    u16x8 pf = ld8(&sP[wave][lr * 32 + lq * 8]);
    o0 = MFMA16(pf, ld8(&sVt[(lr)      * 40 + lq * 8]), o0);
    o1 = MFMA16(pf, ld8(&sVt[(16 + lr) * 40 + lq * 8]), o1);
    o2 = MFMA16(pf, ld8(&sVt[(32 + lr) * 40 + lq * 8]), o2);
    o3 = MFMA16(pf, ld8(&sVt[(48 + lr) * 40 + lq * 8]), o3);
  }

  // reduce l across the 16 lanes holding each row's columns
#pragma unroll
  for (int r = 0; r < 4; r++){
    float l = lsum[r];
    l += __shfl_xor(l, 1); l += __shfl_xor(l, 2);
    l += __shfl_xor(l, 4); l += __shfl_xor(l, 8);
    lsum[r] = l;
  }

  u16* aor = ao + (size_t)(b * 2048 + qt + lq * 4) * 1024 + hh * 64 + lr;
#pragma unroll
  for (int r = 0; r < 4; r++){
    float inv = 1.f / lsum[r];
    u16* p = aor + (size_t)r * 1024;
    p[0]  = f2b(o0[r] * inv);
    p[16] = f2b(o1[r] * inv);
    p[32] = f2b(o2[r] * inv);
    p[48] = f2b(o3[r] * inv);
  }
}

// ---------------------------------------------------------------------------
// Oscillator scan. u fp32 [B,K,T]; tg already sigmoid'ed [B*T,K].
// ---------------------------------------------------------------------------
__global__ __launch_bounds__(256) void scan_k(
    const float* __restrict__ u_t, const float* __restrict__ tg,
    const float* __restrict__ alog, const float* __restrict__ theta,
    u16* __restrict__ z)
{
  const int bk = blockIdx.x;
  const int b = bk >> 5, k = bk & 31;
  const int j = threadIdx.x;
  const float a = 1.f / (1.f + __expf(-alog[k]));
  const float th = theta[k];
  const float wr = a * __cosf(th), wi = a * __sinf(th);
  const float* ubp = u_t + ((size_t)b * 32 + k) * 2048 + j * 8;
  float4 ua = ((const float4*)ubp)[0];
  float4 ub4 = ((const float4*)ubp)[1];
  float ur[8] = {ua.x, ua.y, ua.z, ua.w, ub4.x, ub4.y, ub4.z, ub4.w};
  float sr = 0.f, si = 0.f;
#pragma unroll
  for (int i = 0; i < 8; i++){
    float nr = wr*sr - wi*si + ur[i];
    float ni = wi*sr + wr*si;
    sr = nr; si = ni;
  }
  float w2r = wr*wr - wi*wi, w2i = 2.f*wr*wi;
  float w4r = w2r*w2r - w2i*w2i, w4i = 2.f*w2r*w2i;
  float Ar = w4r*w4r - w4i*w4i, Ai = 2.f*w4r*w4i;   // w^8
  __shared__ float4 sc[256];
  float4 cur; cur.x = Ar; cur.y = Ai; cur.z = sr; cur.w = si;
  sc[j] = cur;
  __syncthreads();
  for (int s = 1; s < 256; s <<= 1){
    float4 pv;
    const bool has = (j >= s);
    if (has) pv = sc[j - s];
    __syncthreads();
    if (has){
      float nar = cur.x*pv.x - cur.y*pv.y;
      float nai = cur.x*pv.y + cur.y*pv.x;
      float nbr = cur.x*pv.z - cur.y*pv.w + cur.z;
      float nbi = cur.x*pv.w + cur.y*pv.z + cur.w;
      cur.x = nar; cur.y = nai; cur.z = nbr; cur.w = nbi;
    }
    sc[j] = cur;
    __syncthreads();
  }
  float s_r = 0.f, s_i = 0.f;
  if (j > 0){ float4 pr = sc[j - 1]; s_r = pr.z; s_i = pr.w; }
  const float* tgp = tg + ((size_t)b * 2048 + j * 8) * 32 + k;
  u16* zp = z + ((size_t)b * 2048 + j * 8) * 32 + k;
#pragma unroll
  for (int i = 0; i < 8; i++){
    float nr = wr*s_r - wi*s_i + ur[i];
    float ni = wi*s_r + wr*s_i;
    s_r = nr; s_i = ni;
    zp[(size_t)i * 32] = f2b(s_r * tgp[(size_t)i * 32]);
  }
}

// ---------------------------------------------------------------------------
extern "C" void kernel_launch(void* const* d_in, const int* in_sizes, int n_in,
                              void* d_out, int out_size, void* d_ws, size_t ws_size,
                              hipStream_t stream)
{
  (void)in_sizes; (void)n_in; (void)out_size; (void)ws_size;
  const float* x      = (const float*)d_in[0];
  const float* n1w    = (const float*)d_in[1];
  const float* qkvw   = (const float*)d_in[2];
  const float* qkvb   = (const float*)d_in[3];
  const float* projw  = (const float*)d_in[4];
  const float* projb  = (const float*)d_in[5];
  const float* gatew  = (const float*)d_in[6];
  const float* gateb  = (const float*)d_in[7];
  const float* twin   = (const float*)d_in[8];
  const float* twout  = (const float*)d_in[9];
  const float* tgw    = (const float*)d_in[10];
  const float* tgb    = (const float*)d_in[11];
  const float* talog  = (const float*)d_in[12];
  const float* ttheta = (const float*)d_in[13];
  const float* tscale = (const float*)d_in[14];
  const float* n2w    = (const float*)d_in[15];
  const float* fgw    = (const float*)d_in[16];
  const float* fuw    = (const float*)d_in[17];
  const float* fdw    = (const float*)d_in[18];
  float* out = (float*)d_out;

  char* wsb = (char*)d_ws;
  size_t off = 0;
  auto take = [&](size_t bytes) -> void* {
    void* r = wsb + off; off += (bytes + 255) & ~(size_t)255; return r;
  };
  u16*   wall = (u16*)take(16941056ull * 2);   // packed bf16 weights
  u16*   h    = (u16*)take(4194304ull * 2);
  u16*   h2   = (u16*)take(4194304ull * 2);
  u16*   trn  = (u16*)take(4194304ull * 2);
  float* g    = (float*)take(4096ull * 4);
  float* u_t  = (float*)take(131072ull * 4);   // TRN drive [B,K,T]
  float* tg   = (float*)take(131072ull * 4);   // sigmoid gate [B*T,K]
  u16*   zz   = (u16*)take(131072ull * 2);
  u16*   regA = (u16*)take(4096ull * 4096 * 2);  // qkv -> proj partials -> down partials
  u16*   regB = (u16*)take(4096ull * 4096 * 2);  // ao  -> act

  u16* wq  = wall;                            // [3200][1024] qkv | trn combined
  u16* wp  = wall + 3276800;
  u16* wgu = wall + 4325376;                  // [8192][1024] group-interleaved
  u16* wd  = wall + 12713984;                 // [1024][4096]
  u16* wo  = wall + 16908288;                 // [1024][32]
  u16* qkv    = regA;
  u16* pproj  = regA;           // 2 x 4096x1024 bf16 partials (after attn read qkv)
  u16* pdown  = regA;           // reused again after reduce_mix_norm
  u16* ao     = regB;
  u16* act    = regB;           // reuses regB after proj GEMM consumed ao

  convert_w<<<16544, 256, 0, stream>>>(qkvw, projw, fgw, fuw, fdw, twin, tgw, twout, wall);
  rmsnorm_gate<<<4096, 256, 0, stream>>>(x, n1w, gatew, gateb, h, g);
  // merged qkv + TRN drive/gate GEMM (N=3200)
  gemm_bt<0, true><<<dim3(32, 25), 256, 0, stream>>>(h, wq, u_t, tg, qkv, qkvb,
                                                     tgb, 0, 3200, 1024);
  attn_win<<<1024, 256, 0, stream>>>(qkv, ao);
  scan_k<<<64, 256, 0, stream>>>(u_t, tg, talog, ttheta, zz);
  gemm_bt<6, false><<<dim3(32, 8), 256, 0, stream>>>(zz, wo, nullptr, nullptr, trn, nullptr,
                                                     tscale, 0, 1024, 32);
  // proj split-K2 -> bf16 partials, then fused reduce+mix+rmsnorm2 (out=xmid, h2)
  gemm_bt<9, true><<<dim3(32, 8, 2), 256, 0, stream>>>(ao, wp, nullptr, nullptr, pproj,
                                                       nullptr, nullptr, 4194304, 1024, 1024);
  reduce_mix_norm<<<4096, 256, 0, stream>>>(pproj, x, trn, g, projb, n2w, out, h2);
  // FFN: merged gate+up, then down split-K2 -> bf16 partials, in-place reduce
  gemm_bt<7, true><<<dim3(32, 64), 256, 0, stream>>>(h2, wgu, nullptr, nullptr, act, nullptr,
                                                     nullptr, 0, 8192, 1024);
  gemm_bt<9, true><<<dim3(32, 8, 2), 256, 0, stream>>>(act, wd, nullptr, nullptr, pdown,
                                                       nullptr, nullptr, 4194304, 1024, 4096);
  reduce_down<<<4096, 256, 0, stream>>>(pdown, out);
}

// Round 7
// 401.389 us; speedup vs baseline: 1.1808x; 1.0426x over previous
//
#include <hip/hip_runtime.h>

// DualMemoryBlock: rmsnorm -> {windowed attn, oscillator TRN} -> gated mix -> SwiGLU FFN
// bf16 MFMA 16x16x32, 128x128 tile, global_load_lds(16B), BK=64 K-loop.
// R7: TRN folded into proj GEMM via K-extension (A' = g*ao | (1-g)*scale*z | 0,
// K=1152); convert+rmsnorm fused; attn+scan+pad fused; 64-key attention tiles.
// 8 dispatches total (was 12).

typedef unsigned short u16;
typedef unsigned short u16x8 __attribute__((ext_vector_type(8)));
typedef __bf16 bf16x8 __attribute__((ext_vector_type(8)));
typedef float f32x4 __attribute__((ext_vector_type(4)));

#define DI static __device__ __forceinline__

DI u16 f2b(float f){
  union { float f; unsigned u; } v; v.f = f;
  unsigned r = v.u + 0x7FFFu + ((v.u >> 16) & 1u);
  return (u16)(r >> 16);
}
DI float b2f(u16 b){
  union { unsigned u; float f; } v; v.u = ((unsigned)b) << 16; return v.f;
}
DI u16x8 ld8(const u16* p){ return *(const u16x8*)p; }

DI f32x4 MFMA16(u16x8 a, u16x8 b, f32x4 c){
  return __builtin_amdgcn_mfma_f32_16x16x32_bf16(
      __builtin_bit_cast(bf16x8, a), __builtin_bit_cast(bf16x8, b), c, 0, 0, 0);
}

DI void async16(const void* g, void* l){
  void* gg = const_cast<void*>(g);
  __builtin_amdgcn_global_load_lds(
      (__attribute__((address_space(1))) void*)gg,
      (__attribute__((address_space(3))) void*)l, 16, 0, 0);
}

// ---------------------------------------------------------------------------
// Fused kernel 1: weight convert (blocks 0..16639) + rmsnorm1/gate (16640..20735)
// Packed bf16 weight layout (element offsets):
//  wq  [3200x1024] qkv | trn_win | trn_gate | 0   0 .. 3276800
//  wpx [1024x1152] proj | wout | 0               3276800 .. 4456448
//  wgu [8192x1024] gate/up group-interleaved     4456448 .. 12845056
//  wd  [1024x4096] down                          12845056 .. 17039360
// ---------------------------------------------------------------------------
__global__ __launch_bounds__(256) void prep_kernel(
    const float* __restrict__ qkvw, const float* __restrict__ projw,
    const float* __restrict__ fgw, const float* __restrict__ fuw,
    const float* __restrict__ fdw, const float* __restrict__ twin,
    const float* __restrict__ tgw, const float* __restrict__ twout,
    u16* __restrict__ dst,
    const float* __restrict__ x, const float* __restrict__ n1w,
    const float* __restrict__ gw, const float* __restrict__ gb,
    u16* __restrict__ h, float* __restrict__ g)
{
  const int blk = blockIdx.x, tid = threadIdx.x;
  if (blk < 16640){
    size_t i = (size_t)blk * 256 + tid;
    if (i >= 4259840u) return;
    size_t e = i * 4;
    float4 v;
    if (e < 3145728u)        v = *(const float4*)(qkvw + e);
    else if (e < 3276800u){
      size_t i2 = e - 3145728u;
      int row = (int)(i2 >> 10), c = (int)(i2 & 1023);
      if (row < 32)      v = *(const float4*)(twin + row * 1024 + c);
      else if (row < 64) v = *(const float4*)(tgw + (row - 32) * 1024 + c);
      else               v = make_float4(0.f, 0.f, 0.f, 0.f);
    }
    else if (e < 4456448u){
      unsigned i2 = (unsigned)(e - 3276800u);
      unsigned row = i2 / 1152u, kk = i2 - row * 1152u;
      if (kk < 1024u)      v = *(const float4*)(projw + (size_t)row * 1024 + kk);
      else if (kk < 1056u) v = *(const float4*)(twout + (size_t)row * 32 + (kk - 1024u));
      else                 v = make_float4(0.f, 0.f, 0.f, 0.f);
    }
    else if (e < 12845056u){
      size_t i2 = e - 4456448u;
      int row = (int)(i2 >> 10), c = (int)(i2 & 1023);
      int G = row >> 5, j = row & 31;
      const float* src = (j < 16) ? fgw : fuw;
      v = *(const float4*)(src + (size_t)(G * 16 + (j & 15)) * 1024 + c);
    }
    else                   v = *(const float4*)(fdw + (e - 12845056u));
    uint2 p;
    p.x = (unsigned)f2b(v.x) | ((unsigned)f2b(v.y) << 16);
    p.y = (unsigned)f2b(v.z) | ((unsigned)f2b(v.w) << 16);
    *(uint2*)(dst + e) = p;
    return;
  }
  // rmsnorm + scalar gate logit
  const int row = blk - 16640;
  const int wave = tid >> 6, lane = tid & 63;
  __shared__ float sb[8];
  float4 xv = ((const float4*)(x + (size_t)row * 1024))[tid];
  float ss = xv.x*xv.x + xv.y*xv.y + xv.z*xv.z + xv.w*xv.w;
#pragma unroll
  for (int m = 32; m; m >>= 1) ss += __shfl_xor(ss, m);
  if (lane == 0) sb[wave] = ss;
  __syncthreads();
  float rstd = rsqrtf((sb[0]+sb[1]+sb[2]+sb[3]) * (1.f/1024.f) + 1e-6f);
  float4 wv = ((const float4*)n1w)[tid];
  float h0 = xv.x*rstd*wv.x, h1 = xv.y*rstd*wv.y;
  float h2v = xv.z*rstd*wv.z, h3 = xv.w*rstd*wv.w;
  uint2 pk;
  pk.x = (unsigned)f2b(h0) | ((unsigned)f2b(h1) << 16);
  pk.y = (unsigned)f2b(h2v) | ((unsigned)f2b(h3) << 16);
  ((uint2*)(h + (size_t)row * 1024))[tid] = pk;
  float4 gv = ((const float4*)gw)[tid];
  float gd = h0*gv.x + h1*gv.y + h2v*gv.z + h3*gv.w;
#pragma unroll
  for (int m = 32; m; m >>= 1) gd += __shfl_xor(gd, m);
  if (lane == 0) sb[4 + wave] = gd;
  __syncthreads();
  if (tid == 0) g[row] = 1.f / (1.f + __expf(-(sb[4]+sb[5]+sb[6]+sb[7] + gb[0])));
}

// ---------------------------------------------------------------------------
// Fused: proj(+TRN) split-K reduce + x + g*projb + rmsnorm2.
// out = x + (p0+p1) + g*projb ; h2 = bf16(rms(out)*n2w)
// ---------------------------------------------------------------------------
__global__ __launch_bounds__(256) void reduce_mix_norm(
    const u16* __restrict__ part, const float* __restrict__ x,
    const float* __restrict__ g, const float* __restrict__ pb,
    const float* __restrict__ n2w,
    float* __restrict__ out, u16* __restrict__ h2)
{
  const int row = blockIdx.x, tid = threadIdx.x;
  const int wave = tid >> 6, lane = tid & 63;
  __shared__ float sb[4];
  const size_t ro = (size_t)row * 1024;
  uint2 a0 = ((const uint2*)(part + ro))[tid];
  uint2 a1 = ((const uint2*)(part + 4194304 + ro))[tid];
  float4 bb = ((const float4*)pb)[tid];
  float4 xv = ((const float4*)(x + ro))[tid];
  float gg = g[row];
  float m0 = xv.x + b2f((u16)a0.x) + b2f((u16)a1.x) + gg*bb.x;
  float m1 = xv.y + b2f((u16)(a0.x >> 16)) + b2f((u16)(a1.x >> 16)) + gg*bb.y;
  float m2 = xv.z + b2f((u16)a0.y) + b2f((u16)a1.y) + gg*bb.z;
  float m3 = xv.w + b2f((u16)(a0.y >> 16)) + b2f((u16)(a1.y >> 16)) + gg*bb.w;
  float4 mo; mo.x = m0; mo.y = m1; mo.z = m2; mo.w = m3;
  ((float4*)(out + ro))[tid] = mo;
  float ss = m0*m0 + m1*m1 + m2*m2 + m3*m3;
#pragma unroll
  for (int m = 32; m; m >>= 1) ss += __shfl_xor(ss, m);
  if (lane == 0) sb[wave] = ss;
  __syncthreads();
  float rstd = rsqrtf((sb[0]+sb[1]+sb[2]+sb[3]) * (1.f/1024.f) + 1e-6f);
  float4 wv = ((const float4*)n2w)[tid];
  uint2 pk;
  pk.x = (unsigned)f2b(m0*rstd*wv.x) | ((unsigned)f2b(m1*rstd*wv.y) << 16);
  pk.y = (unsigned)f2b(m2*rstd*wv.z) | ((unsigned)f2b(m3*rstd*wv.w) << 16);
  ((uint2*)(h2 + ro))[tid] = pk;
}

// Down split-K reduce, in place: out += p0 + p1 (bf16 partials; out holds xmid).
__global__ __launch_bounds__(256) void reduce_down(
    const u16* __restrict__ part, float* __restrict__ out)
{
  size_t i = (size_t)blockIdx.x * 256 + threadIdx.x;
  uint2 a0 = ((const uint2*)part)[i];
  uint2 a1 = ((const uint2*)(part + 4194304))[i];
  float4 xv = ((float4*)out)[i];
  float4 o;
  o.x = xv.x + b2f((u16)a0.x) + b2f((u16)a1.x);
  o.y = xv.y + b2f((u16)(a0.x >> 16)) + b2f((u16)(a1.x >> 16));
  o.z = xv.z + b2f((u16)a0.y) + b2f((u16)a1.y);
  o.w = xv.w + b2f((u16)(a0.y >> 16)) + b2f((u16)(a1.y >> 16));
  ((float4*)out)[i] = o;
}

// ---------------------------------------------------------------------------
// GEMM: out[m,n] = sum_k A[m,k]*B[n,k]  (row-major bf16, fp32 accum)
// 128x128 tile, 256 thr = 2x2 waves; split-K via blockIdx.z.
// WIDE: BK=64 via two 128x32 LDS buffer pairs.
// MODE epilogues:
//  0: n0<3072 -> qkv bf16 + bias (stride 3072);
//     n0==3072 -> TRN drive: c2<32 u[b,k,t]=v; c2<64 tg=sigmoid(v+tgb)
//  7: grouped gate/up: silu(acc[.][2p])*acc[.][2p+1]
//  9: bf16 partial store at z*M + rr*N + col              (split-K partials)
// ---------------------------------------------------------------------------
template<int MODE, bool WIDE>
__global__ __launch_bounds__(256) void gemm_bt(
    const u16* __restrict__ A, const u16* __restrict__ B,
    float* __restrict__ outF, float* __restrict__ outF2, u16* __restrict__ outB,
    const float* __restrict__ bias, const float* __restrict__ auxF,
    int M, int N, int K)
{
  __shared__ __align__(16) u16 sA[2][128 * 32];
  __shared__ __align__(16) u16 sB[2][128 * 32];
  const int tid = threadIdx.x;
  const int wave = tid >> 6, lane = tid & 63;
  const int lr = lane & 15, lq = lane >> 4;
  const int m0 = blockIdx.x * 128, n0 = blockIdx.y * 128;
  const int wm = (wave & 1) * 64, wn = (wave >> 1) * 64;
  const int ks = K / (int)gridDim.z;
  const int kbeg = (int)blockIdx.z * ks, kend = kbeg + ks;
  f32x4 acc[4][4] = {};
  const int srow = wave * 16 + (lane >> 2);
  const int scol = (lane & 3) * 8;
  const u16* gA = A + (size_t)(m0 + srow) * K + scol;
  const u16* gB = B + (size_t)(n0 + srow) * K + scol;
  u16* lA0 = &sA[0][(wave * 16) * 32];
  u16* lA1 = &sA[0][(64 + wave * 16) * 32];
  u16* lB0 = &sB[0][(wave * 16) * 32];
  u16* lB1 = &sB[0][(64 + wave * 16) * 32];
  const size_t K64 = (size_t)64 * K;
  const int BUF = 128 * 32;

  if (WIDE){
    for (int k0 = kbeg; k0 < kend; k0 += 64){
      async16(gA + k0,            lA0);
      async16(gA + K64 + k0,      lA1);
      async16(gB + k0,            lB0);
      async16(gB + K64 + k0,      lB1);
      async16(gA + k0 + 32,       lA0 + BUF);
      async16(gA + K64 + k0 + 32, lA1 + BUF);
      async16(gB + k0 + 32,       lB0 + BUF);
      async16(gB + K64 + k0 + 32, lB1 + BUF);
      __syncthreads();
      u16x8 af[4], bf[4];
#pragma unroll
      for (int i = 0; i < 4; i++) af[i] = ld8(&sA[0][(wm + i*16 + lr)*32 + lq*8]);
#pragma unroll
      for (int i = 0; i < 4; i++) bf[i] = ld8(&sB[0][(wn + i*16 + lr)*32 + lq*8]);
#pragma unroll
      for (int mi = 0; mi < 4; mi++)
#pragma unroll
        for (int ni = 0; ni < 4; ni++)
          acc[mi][ni] = MFMA16(af[mi], bf[ni], acc[mi][ni]);
#pragma unroll
      for (int i = 0; i < 4; i++) af[i] = ld8(&sA[1][(wm + i*16 + lr)*32 + lq*8]);
#pragma unroll
      for (int i = 0; i < 4; i++) bf[i] = ld8(&sB[1][(wn + i*16 + lr)*32 + lq*8]);
#pragma unroll
      for (int mi = 0; mi < 4; mi++)
#pragma unroll
        for (int ni = 0; ni < 4; ni++)
          acc[mi][ni] = MFMA16(af[mi], bf[ni], acc[mi][ni]);
      __syncthreads();
    }
  } else {
    for (int k0 = kbeg; k0 < kend; k0 += 32){
      async16(gA + k0,       lA0);
      async16(gA + K64 + k0, lA1);
      async16(gB + k0,       lB0);
      async16(gB + K64 + k0, lB1);
      __syncthreads();
      u16x8 af[4], bf[4];
#pragma unroll
      for (int i = 0; i < 4; i++) af[i] = ld8(&sA[0][(wm + i*16 + lr)*32 + lq*8]);
#pragma unroll
      for (int i = 0; i < 4; i++) bf[i] = ld8(&sB[0][(wn + i*16 + lr)*32 + lq*8]);
#pragma unroll
      for (int mi = 0; mi < 4; mi++)
#pragma unroll
        for (int ni = 0; ni < 4; ni++)
          acc[mi][ni] = MFMA16(af[mi], bf[ni], acc[mi][ni]);
      __syncthreads();
    }
  }

  if (MODE == 7){
    const int cb = ((n0 + wn) >> 1) + lr;   // packed col base
#pragma unroll
    for (int mi = 0; mi < 4; mi++){
      const int row = m0 + wm + mi*16 + lq*4;
#pragma unroll
      for (int p = 0; p < 2; p++){
        const int col = cb + p*16;
#pragma unroll
        for (int r = 0; r < 4; r++){
          float gv = acc[mi][2*p][r], uv = acc[mi][2*p+1][r];
          float rv = gv / (1.f + __expf(-gv)) * uv;
          outB[(size_t)(row + r) * (N >> 1) + col] = f2b(rv);
        }
      }
    }
    return;
  }

#pragma unroll
  for (int mi = 0; mi < 4; mi++){
    const int row = m0 + wm + mi*16 + lq*4;
#pragma unroll
    for (int ni = 0; ni < 4; ni++){
      const int col = n0 + wn + ni*16 + lr;
#pragma unroll
      for (int r = 0; r < 4; r++){
        const int rr = row + r;
        float v = acc[mi][ni][r];
        if (MODE == 0){
          if (n0 < 3072){
            outB[(size_t)rr * 3072 + col] = f2b(v + bias[col]);
          } else {
            int c2 = col - 3072;
            int bb = rr >> 11, tt = rr & 2047;
            if (c2 < 32) outF[((size_t)bb * 32 + c2) * 2048 + tt] = v;
            else if (c2 < 64)
              outF2[(size_t)rr * 32 + (c2 - 32)] =
                  1.f / (1.f + __expf(-(v + auxF[c2 - 32])));
          }
        } else if (MODE == 9){
          outB[(size_t)blockIdx.z * (size_t)M + (size_t)rr * N + col] = f2b(v);
        }
      }
    }
  }
}

// ---------------------------------------------------------------------------
// Fused kernel 2: windowed attention (blocks 0..1023, 64-key tiles, no online
// max; output pre-scaled by g into A' stride 1152) + oscillator scan (blocks
// 1024..1087; z pre-scaled by (1-g)*res_scale into A' cols 1024..1055) +
// zero-fill of A' pad cols 1056..1151 (blocks 1088..1279).
// ---------------------------------------------------------------------------
__global__ __launch_bounds__(256) void attn_scan(
    const u16* __restrict__ qkv, const float* __restrict__ g,
    const float* __restrict__ u_t, const float* __restrict__ tg,
    const float* __restrict__ alog, const float* __restrict__ theta,
    const float* __restrict__ tscale, u16* __restrict__ Ap)
{
  __shared__ __align__(16) u16 sVt[64 * 72];      // V^T [dim][key], pad 72
  __shared__ __align__(16) u16 sP[4][16 * 72];    // per-wave P, pad 72
  __shared__ float4 sc[256];                       // scan
  const int blk = blockIdx.x, tid = threadIdx.x;

  if (blk < 1024){
    const int tile = blk & 31, hh = (blk >> 5) & 15, b = blk >> 9;
    const int t0 = tile * 64;
    const int wave = tid >> 6, lane = tid & 63;
    const int lr = lane & 15, lq = lane >> 4;
    const int qt = t0 + wave * 16;

    const u16* base = qkv + (size_t)b * 2048 * 3072 + hh * 64;
    const u16* qrow = base + (size_t)(qt + lr) * 3072 + lq * 8;
    u16x8 qf0 = ld8(qrow), qf1 = ld8(qrow + 32);
    const u16* kbase = base + 1024;
    const u16* vbase = base + 2048;

    f32x4 o0 = {0,0,0,0}, o1 = {0,0,0,0}, o2 = {0,0,0,0}, o3 = {0,0,0,0};
    float lsum[4] = {0.f, 0.f, 0.f, 0.f};
    const float c1 = 0.125f * 1.44269504088896f;  // scale * log2(e)

    const int kb = (t0 >= 256) ? (t0 - 256) : 0;
    const int ntl = (t0 + 64 - kb) >> 6;
    for (int it = 0; it < ntl; ++it){
      const int kt = kb + it * 64;
      __syncthreads();               // prev-iter LDS reads done
      {                              // stage V^T: 64 keys x 64 dims, 16 el/thread
        const int key = tid & 63, dseg = tid >> 6;   // dseg: 16-dim segment
        const u16* gv = vbase + (size_t)(kt + key) * 3072 + dseg * 16;
        u16x8 v0 = ld8(gv), v1 = ld8(gv + 8);
#pragma unroll
        for (int j = 0; j < 8; j++){
          sVt[(dseg*16 + j)     * 72 + key] = v0[j];
          sVt[(dseg*16 + 8 + j) * 72 + key] = v1[j];
        }
      }
      __syncthreads();
      const bool active = (kt < qt + 16) && (kt + 318 >= qt);
      if (!active) continue;         // both barriers above: counts stay equal

      f32x4 s[4] = {};
#pragma unroll
      for (int gK = 0; gK < 4; gK++){
        const u16* kr = kbase + (size_t)(kt + gK*16 + lr) * 3072 + lq * 8;
        u16x8 k0 = ld8(kr), k1 = ld8(kr + 32);
        s[gK] = MFMA16(qf0, k0, s[gK]);
        s[gK] = MFMA16(qf1, k1, s[gK]);
      }
#pragma unroll
      for (int r = 0; r < 4; r++){
        const int q = qt + lq * 4 + r;
#pragma unroll
        for (int gK = 0; gK < 4; gK++){
          const int c = kt + gK*16 + lr;
          float p = (c <= q && c + 255 >= q) ? exp2f(s[gK][r] * c1) : 0.f;
          lsum[r] += p;
          sP[wave][(lq*4 + r) * 72 + gK*16 + lr] = f2b(p);
        }
      }
      __builtin_amdgcn_s_waitcnt(0xc07f);   // lgkmcnt(0): P writes visible
      u16x8 pf0 = ld8(&sP[wave][lr * 72 + lq * 8]);
      u16x8 pf1 = ld8(&sP[wave][lr * 72 + 32 + lq * 8]);
      o0 = MFMA16(pf0, ld8(&sVt[(lr)      * 72 + lq * 8]), o0);
      o0 = MFMA16(pf1, ld8(&sVt[(lr)      * 72 + 32 + lq * 8]), o0);
      o1 = MFMA16(pf0, ld8(&sVt[(16 + lr) * 72 + lq * 8]), o1);
      o1 = MFMA16(pf1, ld8(&sVt[(16 + lr) * 72 + 32 + lq * 8]), o1);
      o2 = MFMA16(pf0, ld8(&sVt[(32 + lr) * 72 + lq * 8]), o2);
      o2 = MFMA16(pf1, ld8(&sVt[(32 + lr) * 72 + 32 + lq * 8]), o2);
      o3 = MFMA16(pf0, ld8(&sVt[(48 + lr) * 72 + lq * 8]), o3);
      o3 = MFMA16(pf1, ld8(&sVt[(48 + lr) * 72 + 32 + lq * 8]), o3);
    }

#pragma unroll
    for (int r = 0; r < 4; r++){
      float l = lsum[r];
      l += __shfl_xor(l, 1); l += __shfl_xor(l, 2);
      l += __shfl_xor(l, 4); l += __shfl_xor(l, 8);
      lsum[r] = l;
    }

    const int trow = b * 2048 + qt + lq * 4;
    u16* aor = Ap + (size_t)trow * 1152 + hh * 64 + lr;
#pragma unroll
    for (int r = 0; r < 4; r++){
      float inv = g[trow + r] / lsum[r];    // pre-scale by gate g
      u16* p = aor + (size_t)r * 1152;
      p[0]  = f2b(o0[r] * inv);
      p[16] = f2b(o1[r] * inv);
      p[32] = f2b(o2[r] * inv);
      p[48] = f2b(o3[r] * inv);
    }
    return;
  }

  if (blk < 1088){
    // oscillator scan for (b,k); z pre-scaled by (1-g)*res_scale into A'
    const int bk = blk - 1024;
    const int b = bk >> 5, k = bk & 31;
    const int j = tid;
    const float a = 1.f / (1.f + __expf(-alog[k]));
    const float th = theta[k];
    const float rs = tscale[0];
    const float wr = a * __cosf(th), wi = a * __sinf(th);
    const float* ubp = u_t + ((size_t)b * 32 + k) * 2048 + j * 8;
    float4 ua = ((const float4*)ubp)[0];
    float4 ub4 = ((const float4*)ubp)[1];
    float ur[8] = {ua.x, ua.y, ua.z, ua.w, ub4.x, ub4.y, ub4.z, ub4.w};
    float sr = 0.f, si = 0.f;
#pragma unroll
    for (int i = 0; i < 8; i++){
      float nr = wr*sr - wi*si + ur[i];
      float ni = wi*sr + wr*si;
      sr = nr; si = ni;
    }
    float w2r = wr*wr - wi*wi, w2i = 2.f*wr*wi;
    float w4r = w2r*w2r - w2i*w2i, w4i = 2.f*w2r*w2i;
    float Ar = w4r*w4r - w4i*w4i, Ai = 2.f*w4r*w4i;   // w^8
    float4 cur; cur.x = Ar; cur.y = Ai; cur.z = sr; cur.w = si;
    sc[j] = cur;
    __syncthreads();
    for (int s = 1; s < 256; s <<= 1){
      float4 pv;
      const bool has = (j >= s);
      if (has) pv = sc[j - s];
      __syncthreads();
      if (has){
        float nar = cur.x*pv.x - cur.y*pv.y;
        float nai = cur.x*pv.y + cur.y*pv.x;
        float nbr = cur.x*pv.z - cur.y*pv.w + cur.z;
        float nbi = cur.x*pv.w + cur.y*pv.z + cur.w;
        cur.x = nar; cur.y = nai; cur.z = nbr; cur.w = nbi;
      }
      sc[j] = cur;
      __syncthreads();
    }
    float s_r = 0.f, s_i = 0.f;
    if (j > 0){ float4 pr = sc[j - 1]; s_r = pr.z; s_i = pr.w; }
    const int bt0 = b * 2048 + j * 8;
    const float* tgp = tg + (size_t)bt0 * 32 + k;
    u16* zp = Ap + (size_t)bt0 * 1152 + 1024 + k;
#pragma unroll
    for (int i = 0; i < 8; i++){
      float nr = wr*s_r - wi*s_i + ur[i];
      float ni = wi*s_r + wr*s_i;
      s_r = nr; s_i = ni;
      float sc2 = (1.f - g[bt0 + i]) * rs;
      zp[(size_t)i * 1152] = f2b(s_r * tgp[(size_t)i * 32] * sc2);
    }
    return;
  }

  // zero-fill A' pad cols 1056..1151 (96 u16 per row, 8 per thread)
  {
    unsigned idx = (unsigned)(blk - 1088) * 256 + tid;   // < 49152
    unsigned row = idx / 12u, seg = idx - row * 12u;
    uint4 z4; z4.x = 0; z4.y = 0; z4.z = 0; z4.w = 0;
    *(uint4*)(Ap + (size_t)row * 1152 + 1056 + seg * 8) = z4;
  }
}

// ---------------------------------------------------------------------------
extern "C" void kernel_launch(void* const* d_in, const int* in_sizes, int n_in,
                              void* d_out, int out_size, void* d_ws, size_t ws_size,
                              hipStream_t stream)
{
  (void)in_sizes; (void)n_in; (void)out_size; (void)ws_size;
  const float* x      = (const float*)d_in[0];
  const float* n1w    = (const float*)d_in[1];
  const float* qkvw   = (const float*)d_in[2];
  const float* qkvb   = (const float*)d_in[3];
  const float* projw  = (const float*)d_in[4];
  const float* projb  = (const float*)d_in[5];
  const float* gatew  = (const float*)d_in[6];
  const float* gateb  = (const float*)d_in[7];
  const float* twin   = (const float*)d_in[8];
  const float* twout  = (const float*)d_in[9];
  const float* tgw    = (const float*)d_in[10];
  const float* tgb    = (const float*)d_in[11];
  const float* talog  = (const float*)d_in[12];
  const float* ttheta = (const float*)d_in[13];
  const float* tscale = (const float*)d_in[14];
  const float* n2w    = (const float*)d_in[15];
  const float* fgw    = (const float*)d_in[16];
  const float* fuw    = (const float*)d_in[17];
  const float* fdw    = (const float*)d_in[18];
  float* out = (float*)d_out;

  char* wsb = (char*)d_ws;
  size_t off = 0;
  auto take = [&](size_t bytes) -> void* {
    void* r = wsb + off; off += (bytes + 255) & ~(size_t)255; return r;
  };
  u16*   wall = (u16*)take(17039360ull * 2);   // packed bf16 weights
  u16*   h    = (u16*)take(4194304ull * 2);
  u16*   h2   = (u16*)take(4194304ull * 2);
  float* g    = (float*)take(4096ull * 4);
  float* u_t  = (float*)take(131072ull * 4);   // TRN drive [B,K,T]
  float* tg   = (float*)take(131072ull * 4);   // sigmoid gate [B*T,K]
  u16*   regA = (u16*)take(4096ull * 4096 * 2);  // qkv -> proj partials -> down partials
  u16*   regB = (u16*)take(4096ull * 4096 * 2);  // A' [4096x1152] -> act

  u16* wq  = wall;                            // [3200][1024] qkv | trn combined
  u16* wpx = wall + 3276800;                  // [1024][1152] proj | wout | 0
  u16* wgu = wall + 4456448;                  // [8192][1024] group-interleaved
  u16* wd  = wall + 12845056;                 // [1024][4096]
  u16* qkv    = regA;
  u16* pproj  = regA;           // 2 x 4096x1024 bf16 partials (qkv dead after attn)
  u16* pdown  = regA;           // reused again after reduce_mix_norm
  u16* Ap     = regB;           // A' [4096 x 1152]: g*ao | (1-g)*rs*z | 0
  u16* act    = regB;           // reuses regB after proj GEMM consumed A'

  prep_kernel<<<20736, 256, 0, stream>>>(qkvw, projw, fgw, fuw, fdw, twin, tgw,
                                         twout, wall, x, n1w, gatew, gateb, h, g);
  // merged qkv + TRN drive/gate GEMM (N=3200)
  gemm_bt<0, true><<<dim3(32, 25), 256, 0, stream>>>(h, wq, u_t, tg, qkv, qkvb,
                                                     tgb, 0, 3200, 1024);
  // attention (64-key tiles, g-prescaled) + scan + pad into A'
  attn_scan<<<1280, 256, 0, stream>>>(qkv, g, u_t, tg, talog, ttheta, tscale, Ap);
  // proj(+TRN) split-K2 over K=1152 -> bf16 partials, then reduce+norm2
  gemm_bt<9, true><<<dim3(32, 8, 2), 256, 0, stream>>>(Ap, wpx, nullptr, nullptr, pproj,
                                                       nullptr, nullptr, 4194304, 1024, 1152);
  reduce_mix_norm<<<4096, 256, 0, stream>>>(pproj, x, g, projb, n2w, out, h2);
  // FFN: merged gate+up, then down split-K2 -> bf16 partials, in-place reduce
  gemm_bt<7, true><<<dim3(32, 64), 256, 0, stream>>>(h2, wgu, nullptr, nullptr, act, nullptr,
                                                     nullptr, 0, 8192, 1024);
  gemm_bt<9, true><<<dim3(32, 8, 2), 256, 0, stream>>>(act, wd, nullptr, nullptr, pdown,
                                                       nullptr, nullptr, 4194304, 1024, 4096);
  reduce_down<<<4096, 256, 0, stream>>>(pdown, out);
}